// Round 2
// baseline (1171.694 us; speedup 1.0000x reference)
//
#include <hip/hip_runtime.h>
#include <hip/hip_bf16.h>

#define NN 10000
#define EE 320000
#define ETOT (EE + NN)
#define CIN 256
#define HC 512
#define NHEAD 8
#define NEG 0.2f

// ---------------- dtype detect: bf16 vs fp32 float inputs -------------------
// Genuine bf16 N(0,1) data: exponent field <= ~0x82. fp32 data read as
// halfwords: low mantissa halves have uniform-random exponent fields ->
// virtually certain to exceed 0xC8 within 512 halfwords.
__global__ void detect_k(const unsigned short* __restrict__ x, int* __restrict__ flag) {
  if (threadIdx.x == 0 && blockIdx.x == 0) {
    int isbf16 = 1;
    for (int i = 0; i < 512; i++) {
      unsigned e = (x[i] >> 7) & 0xFFu;
      if (e >= 0xC8u) { isbf16 = 0; break; }
    }
    *flag = isbf16;
  }
}

// convert a float input (bf16 or fp32 per flag) to an fp32 workspace copy
__global__ void cvt_k(const void* __restrict__ src, float* __restrict__ dst, int n,
                      const int* __restrict__ flag) {
  int i = blockIdx.x * blockDim.x + threadIdx.x;
  if (i >= n) return;
  if (*flag)
    dst[i] = __bfloat162float(((const __hip_bfloat16*)src)[i]);
  else
    dst[i] = ((const float*)src)[i];
}

// monotonic float -> uint key (order-preserving for all non-NaN floats)
__device__ __forceinline__ unsigned fkey(float f) {
  unsigned u = __float_as_uint(f);
  return u ^ ((u >> 31) ? 0xFFFFFFFFu : 0x80000000u);
}
__device__ __forceinline__ float fkeyinv(unsigned k) {
  return __uint_as_float((k & 0x80000000u) ? (k ^ 0x80000000u) : ~k);
}

// ---------------- GEMM: C[M,Nc] = A[M,K] @ B[K,Nc], fp32 -------------------
__global__ __launch_bounds__(256) void gemm_k(const float* __restrict__ A,
                                              const float* __restrict__ B,
                                              float* __restrict__ C,
                                              int M, int Nc, int K) {
  __shared__ float As[16][65];
  __shared__ float Bs[16][65];
  const int bm = blockIdx.y * 64, bn = blockIdx.x * 64;
  const int tid = threadIdx.x;
  const int tm = (tid >> 4) * 4, tn = (tid & 15) * 4;
  float acc[4][4] = {};
  for (int k0 = 0; k0 < K; k0 += 16) {
    for (int i = tid; i < 64 * 16; i += 256) {
      int m = i >> 4, k = i & 15;
      int gm = bm + m;
      As[k][m] = (gm < M) ? A[(size_t)gm * K + k0 + k] : 0.f;
    }
    for (int i = tid; i < 16 * 64; i += 256) {
      int k = i >> 6, n = i & 63;
      Bs[k][n] = B[(size_t)(k0 + k) * Nc + bn + n];
    }
    __syncthreads();
#pragma unroll
    for (int k = 0; k < 16; k++) {
      float a[4], b[4];
#pragma unroll
      for (int i = 0; i < 4; i++) a[i] = As[k][tm + i];
#pragma unroll
      for (int j = 0; j < 4; j++) b[j] = Bs[k][tn + j];
#pragma unroll
      for (int i = 0; i < 4; i++)
#pragma unroll
        for (int j = 0; j < 4; j++) acc[i][j] += a[i] * b[j];
    }
    __syncthreads();
  }
  for (int i = 0; i < 4; i++) {
    int gm = bm + tm + i;
    if (gm < M)
      for (int j = 0; j < 4; j++) C[(size_t)gm * Nc + bn + tn + j] = acc[i][j];
  }
}

// ---------------- attention logits: al_src/al_dst [N,H] --------------------
__global__ void logits_k(const float* __restrict__ hbuf,
                         const float* __restrict__ as_w,
                         const float* __restrict__ ad_w,
                         float* __restrict__ alsrc, float* __restrict__ aldst) {
  int idx = blockIdx.x * blockDim.x + threadIdx.x;
  if (idx >= NN * NHEAD) return;
  int n = idx >> 3, h = idx & 7;
  const float* hp = hbuf + (size_t)n * HC + h * 64;
  float s = 0.f, d = 0.f;
#pragma unroll 8
  for (int c = 0; c < 64; c++) {
    float v = hp[c];
    s += v * as_w[h * 64 + c];
    d += v * ad_w[h * 64 + c];
  }
  alsrc[idx] = s;
  aldst[idx] = d;
}

// ---------------- CSR build ------------------------------------------------
__global__ void count_k(const int* __restrict__ ei, int* __restrict__ counts) {
  int e = blockIdx.x * blockDim.x + threadIdx.x;
  if (e >= ETOT) return;
  int d = (e < EE) ? ei[EE + e] : (e - EE);
  atomicAdd(&counts[d], 1);
}

__global__ void scan_k(const int* __restrict__ counts, int* __restrict__ rowptr) {
  __shared__ int buf[1024];
  const int t = threadIdx.x;
  int base = 0;
  for (int c0 = 0; c0 < NN; c0 += 1024) {
    int i = c0 + t;
    int v = (i < NN) ? counts[i] : 0;
    buf[t] = v;
    __syncthreads();
    for (int off = 1; off < 1024; off <<= 1) {
      int tv = (t >= off) ? buf[t - off] : 0;
      __syncthreads();
      buf[t] += tv;
      __syncthreads();
    }
    if (i < NN) rowptr[i + 1] = base + buf[t];
    base += buf[1023];
    __syncthreads();
  }
  if (t == 0) rowptr[0] = 0;
}

__global__ void fill_k(const int* __restrict__ ei, const int* __restrict__ rowptr,
                       int* __restrict__ cursor, int* __restrict__ eids) {
  int e = blockIdx.x * blockDim.x + threadIdx.x;
  if (e >= ETOT) return;
  int d = (e < EE) ? ei[EE + e] : (e - EE);
  int pos = atomicAdd(&cursor[d], 1);
  eids[rowptr[d] + pos] = e;
}

// ---------------- edge pass 1: raw alpha + segment max ---------------------
__global__ void edge1_k(const int* __restrict__ ei,
                        const float* __restrict__ ew,
                        const float* __restrict__ alsrc, const float* __restrict__ aldst,
                        float* __restrict__ alpha, unsigned* __restrict__ amax) {
  int e = blockIdx.x * blockDim.x + threadIdx.x;
  if (e >= ETOT) return;
  int s, d;
  float lw;
  if (e < EE) {
    s = ei[e];
    d = ei[EE + e];
    lw = log2f(ew[e]);
  } else {
    s = d = e - EE;
    lw = 0.f;
  }
#pragma unroll
  for (int h = 0; h < NHEAD; h++) {
    float a = alsrc[s * NHEAD + h] + aldst[d * NHEAD + h];
    a = (a > 0.f) ? a : NEG * a;
    a += lw;
    alpha[(size_t)e * NHEAD + h] = a;
    atomicMax(&amax[d * NHEAD + h], fkey(a));
  }
}

// ---------------- edge pass 2: exp + segment denom -------------------------
__global__ void edge2_k(const int* __restrict__ ei, const unsigned* __restrict__ amax,
                        float* __restrict__ alpha, float* __restrict__ denom) {
  int e = blockIdx.x * blockDim.x + threadIdx.x;
  if (e >= ETOT) return;
  int d = (e < EE) ? ei[EE + e] : (e - EE);
#pragma unroll
  for (int h = 0; h < NHEAD; h++) {
    float m = fkeyinv(amax[d * NHEAD + h]);
    float ex = expf(alpha[(size_t)e * NHEAD + h] - m);
    alpha[(size_t)e * NHEAD + h] = ex;
    atomicAdd(&denom[d * NHEAD + h], ex);
  }
}

// ---------------- aggregation: one block per dst node ----------------------
template <bool RELU, bool FINAL>
__global__ __launch_bounds__(256) void agg_k(const float* __restrict__ hbuf,
                                             const float* __restrict__ alpha,
                                             const float* __restrict__ denom,
                                             const int* __restrict__ rowptr,
                                             const int* __restrict__ eids,
                                             const int* __restrict__ ei,
                                             const float* __restrict__ bias,
                                             float* __restrict__ outF,
                                             __hip_bfloat16* __restrict__ outB,
                                             const int* __restrict__ flag) {
  const int n = blockIdx.x;
  const int t = threadIdx.x;
  __shared__ float sden[NHEAD];
  if (t < NHEAD) sden[t] = denom[n * NHEAD + t];
  __syncthreads();
  const int h0 = t >> 6, h1 = (t + 256) >> 6;
  float acc0 = 0.f, acc1 = 0.f;
  const int beg = rowptr[n], end = rowptr[n + 1];
  for (int i = beg; i < end; i++) {
    int e = eids[i];
    int s = (e < EE) ? ei[e] : (e - EE);
    float w0 = alpha[(size_t)e * NHEAD + h0];
    float w1 = alpha[(size_t)e * NHEAD + h1];
    const float* hp = hbuf + (size_t)s * HC;
    acc0 += w0 * hp[t];
    acc1 += w1 * hp[t + 256];
  }
  float v0 = acc0 / sden[h0] + bias[t];
  float v1 = acc1 / sden[h1] + bias[t + 256];
  if (RELU) {
    v0 = fmaxf(v0, 0.f);
    v1 = fmaxf(v1, 0.f);
  }
  const size_t o0 = (size_t)n * HC + t, o1 = o0 + 256;
  if (FINAL) {
    if (*flag) {
      outB[o0] = __float2bfloat16(v0);
      outB[o1] = __float2bfloat16(v1);
    } else {
      outF[o0] = v0;
      outF[o1] = v1;
    }
  } else {
    outF[o0] = v0;
    outF[o1] = v1;
  }
}

// ---------------- workspace layout -----------------------------------------
static constexpr size_t algn(size_t x) { return (x + 255) & ~(size_t)255; }
static constexpr size_t sH = (size_t)NN * HC * 4;        // h buffer (fp32)
static constexpr size_t sAl = (size_t)ETOT * NHEAD * 4;  // alpha
static constexpr size_t sNH = (size_t)NN * NHEAD * 4;    // [N,H] fp32/u32
static constexpr size_t oH = 0;
static constexpr size_t oO1 = algn(oH + sH);
static constexpr size_t oAl = algn(oO1 + sH);
static constexpr size_t oAS = algn(oAl + sAl);
static constexpr size_t oAD = algn(oAS + sNH);
static constexpr size_t oMax = algn(oAD + sNH);
static constexpr size_t oDen = algn(oMax + sNH);
static constexpr size_t oRP = algn(oDen + sNH);
static constexpr size_t oCur = algn(oRP + (size_t)(NN + 1) * 4);
static constexpr size_t oEid = algn(oCur + (size_t)NN * 4);
// fp32 copies of float inputs
static constexpr size_t oXF = algn(oEid + (size_t)ETOT * 4);
static constexpr size_t oEWF = algn(oXF + (size_t)NN * CIN * 4);
static constexpr size_t oW1F = algn(oEWF + (size_t)EE * 4);
static constexpr size_t oW2F = algn(oW1F + (size_t)CIN * HC * 4);
static constexpr size_t oAtt = algn(oW2F + (size_t)HC * HC * 4);  // as1,ad1,b1,as2,ad2,b2
static constexpr size_t oFlag = algn(oAtt + 6 * 512 * 4);

extern "C" void kernel_launch(void* const* d_in, const int* in_sizes, int n_in,
                              void* d_out, int out_size, void* d_ws, size_t ws_size,
                              hipStream_t stream) {
  (void)in_sizes; (void)n_in; (void)out_size; (void)ws_size;
  const int* ei = (const int*)d_in[1];

  char* ws = (char*)d_ws;
  float* hbuf = (float*)(ws + oH);
  float* o1 = (float*)(ws + oO1);
  float* alpha = (float*)(ws + oAl);
  float* alsrc = (float*)(ws + oAS);
  float* aldst = (float*)(ws + oAD);
  unsigned* amax = (unsigned*)(ws + oMax);
  float* denom = (float*)(ws + oDen);
  int* rowptr = (int*)(ws + oRP);
  int* cursor = (int*)(ws + oCur);
  int* eids = (int*)(ws + oEid);
  float* xf = (float*)(ws + oXF);
  float* ewf = (float*)(ws + oEWF);
  float* w1f = (float*)(ws + oW1F);
  float* w2f = (float*)(ws + oW2F);
  float* attf = (float*)(ws + oAtt);
  float* as1f = attf, *ad1f = attf + 512, *b1f = attf + 1024;
  float* as2f = attf + 1536, *ad2f = attf + 2048, *b2f = attf + 2560;
  int* flag = (int*)(ws + oFlag);

  const int eb = (ETOT + 255) / 256;

  // ---- dtype detect + fp32 conversion of all float inputs ----
  detect_k<<<1, 64, 0, stream>>>((const unsigned short*)d_in[0], flag);
  cvt_k<<<(NN * CIN + 255) / 256, 256, 0, stream>>>(d_in[0], xf, NN * CIN, flag);
  cvt_k<<<(EE + 255) / 256, 256, 0, stream>>>(d_in[2], ewf, EE, flag);
  cvt_k<<<(CIN * HC + 255) / 256, 256, 0, stream>>>(d_in[3], w1f, CIN * HC, flag);
  cvt_k<<<2, 256, 0, stream>>>(d_in[4], as1f, 512, flag);
  cvt_k<<<2, 256, 0, stream>>>(d_in[5], ad1f, 512, flag);
  cvt_k<<<2, 256, 0, stream>>>(d_in[6], b1f, 512, flag);
  cvt_k<<<(HC * HC + 255) / 256, 256, 0, stream>>>(d_in[7], w2f, HC * HC, flag);
  cvt_k<<<2, 256, 0, stream>>>(d_in[8], as2f, 512, flag);
  cvt_k<<<2, 256, 0, stream>>>(d_in[9], ad2f, 512, flag);
  cvt_k<<<2, 256, 0, stream>>>(d_in[10], b2f, 512, flag);

  // ---- CSR build (shared by both layers) ----
  hipMemsetAsync(cursor, 0, (size_t)NN * 4, stream);
  count_k<<<eb, 256, 0, stream>>>(ei, cursor);
  scan_k<<<1, 1024, 0, stream>>>(cursor, rowptr);
  hipMemsetAsync(cursor, 0, (size_t)NN * 4, stream);
  fill_k<<<eb, 256, 0, stream>>>(ei, rowptr, cursor, eids);

  // ---- layer 1 ----
  gemm_k<<<dim3(HC / 64, (NN + 63) / 64), 256, 0, stream>>>(xf, w1f, hbuf, NN, HC, CIN);
  logits_k<<<(NN * NHEAD + 255) / 256, 256, 0, stream>>>(hbuf, as1f, ad1f, alsrc, aldst);
  hipMemsetAsync(amax, 0, sNH, stream);
  hipMemsetAsync(denom, 0, sNH, stream);
  edge1_k<<<eb, 256, 0, stream>>>(ei, ewf, alsrc, aldst, alpha, amax);
  edge2_k<<<eb, 256, 0, stream>>>(ei, amax, alpha, denom);
  agg_k<true, false><<<NN, 256, 0, stream>>>(hbuf, alpha, denom, rowptr, eids, ei,
                                             b1f, o1, nullptr, flag);

  // ---- layer 2 ----
  gemm_k<<<dim3(HC / 64, (NN + 63) / 64), 256, 0, stream>>>(o1, w2f, hbuf, NN, HC, HC);
  logits_k<<<(NN * NHEAD + 255) / 256, 256, 0, stream>>>(hbuf, as2f, ad2f, alsrc, aldst);
  hipMemsetAsync(amax, 0, sNH, stream);
  hipMemsetAsync(denom, 0, sNH, stream);
  edge1_k<<<eb, 256, 0, stream>>>(ei, ewf, alsrc, aldst, alpha, amax);
  edge2_k<<<eb, 256, 0, stream>>>(ei, amax, alpha, denom);
  agg_k<false, true><<<NN, 256, 0, stream>>>(hbuf, alpha, denom, rowptr, eids, ei,
                                             b2f, (float*)d_out, (__hip_bfloat16*)d_out, flag);
}

// Round 4
// 410.617 us; speedup vs baseline: 2.8535x; 2.8535x over previous
//
#include <hip/hip_runtime.h>
#include <hip/hip_bf16.h>

#define NN 10000
#define EE 320000
#define ETOT (EE + NN)
#define CIN 256
#define HC 512
#define NHEAD 8
#define NEG 0.2f

using bf16x8 = __attribute__((ext_vector_type(8))) short;
using f32x4 = __attribute__((ext_vector_type(4))) float;
typedef unsigned short u16;
typedef unsigned int u32;

// ---------------- dtype detect: bf16 vs fp32 float inputs -------------------
__global__ void detect_k(const u16* __restrict__ x, int* __restrict__ flag) {
  if (threadIdx.x == 0 && blockIdx.x == 0) {
    int isbf16 = 1;
    for (int i = 0; i < 512; i++) {
      unsigned e = (x[i] >> 7) & 0xFFu;
      if (e >= 0xC8u) { isbf16 = 0; break; }
    }
    *flag = isbf16;
  }
}

// convert float input -> bf16 workspace copy
__global__ void cvtb_k(const void* __restrict__ src, u16* __restrict__ dst, int n,
                       const int* __restrict__ flag) {
  int i = blockIdx.x * blockDim.x + threadIdx.x;
  if (i >= n) return;
  if (*flag) {
    dst[i] = ((const u16*)src)[i];
  } else {
    __hip_bfloat16 b = __float2bfloat16(((const float*)src)[i]);
    dst[i] = *(u16*)&b;
  }
}

// convert 6 small float inputs -> fp32 (as1,ad1,b1,as2,ad2,b2; 512 each)
__global__ void cvt6_k(const void* p0, const void* p1, const void* p2,
                       const void* p3, const void* p4, const void* p5,
                       float* __restrict__ dst, const int* __restrict__ flag) {
  int i = blockIdx.x * blockDim.x + threadIdx.x;
  if (i >= 6 * 512) return;
  const void* ps[6] = {p0, p1, p2, p3, p4, p5};
  const void* p = ps[i >> 9];
  int j = i & 511;
  dst[i] = (*flag) ? __bfloat162float(((const __hip_bfloat16*)p)[j])
                   : ((const float*)p)[j];
}

// ---------------- MFMA GEMM: C[M,512] = A[M,K] @ B[K,512], bf16 in fp32 out -
#define BM 128
#define BN 64
#define BK 32
#define APAD 40
#define BPAD 40

__global__ __launch_bounds__(256) void gemm_mfma(const u16* __restrict__ A,
                                                 const u16* __restrict__ B,
                                                 float* __restrict__ C,
                                                 int M, int K) {
  __shared__ u16 As[BM * APAD];
  __shared__ u16 Bs[BN * BPAD];
  const int bm = blockIdx.y * BM, bn = blockIdx.x * BN;
  const int t = threadIdx.x;
  const int wave = t >> 6, lane = t & 63;
  const int l15 = lane & 15, quad = lane >> 4;
  f32x4 acc[2][4] = {};
  for (int k0 = 0; k0 < K; k0 += BK) {
    // stage A: 128 rows x 32 cols bf16 (64 B/row). thread t -> row t>>1,
    // half t&1 covering 16 elements = two int4 (FIX: was one int4 -> half
    // the tile uninitialized -> NaN from stale LDS).
    {
      int row = t >> 1, half = t & 1;
      int gr = bm + row;
      int4 v0 = make_int4(0, 0, 0, 0), v1 = v0;
      if (gr < M) {
        const int4* gp = (const int4*)(A + (size_t)gr * K + k0 + half * 16);
        v0 = gp[0];
        v1 = gp[1];
      }
      int4* lp = (int4*)(As + row * APAD + half * 16);
      lp[0] = v0;
      lp[1] = v1;
    }
    // stage B transposed (n-major): k-pair packed u32 writes
    {
      int n = t & 63;
#pragma unroll
      for (int j = 0; j < 4; j++) {
        int kp = (t >> 6) + j * 4;  // 0..15
        int k = kp * 2;
        u16 b0 = B[(size_t)(k0 + k) * HC + bn + n];
        u16 b1 = B[(size_t)(k0 + k + 1) * HC + bn + n];
        *(u32*)(Bs + n * BPAD + k) = (u32)b0 | ((u32)b1 << 16);
      }
    }
    __syncthreads();
    bf16x8 af[2], bfr[4];
#pragma unroll
    for (int rt = 0; rt < 2; rt++)
      af[rt] = *(const bf16x8*)(As + (wave * 32 + rt * 16 + l15) * APAD + quad * 8);
#pragma unroll
    for (int ct = 0; ct < 4; ct++)
      bfr[ct] = *(const bf16x8*)(Bs + (ct * 16 + l15) * BPAD + quad * 8);
#pragma unroll
    for (int rt = 0; rt < 2; rt++)
#pragma unroll
      for (int ct = 0; ct < 4; ct++)
        acc[rt][ct] = __builtin_amdgcn_mfma_f32_16x16x32_bf16(af[rt], bfr[ct],
                                                              acc[rt][ct], 0, 0, 0);
    __syncthreads();
  }
  // epilogue: D row = quad*4 + reg, col = lane&15 (m89-verified layout)
#pragma unroll
  for (int rt = 0; rt < 2; rt++) {
#pragma unroll
    for (int r = 0; r < 4; r++) {
      int row = bm + wave * 32 + rt * 16 + quad * 4 + r;
      if (row < M) {
#pragma unroll
        for (int ct = 0; ct < 4; ct++)
          C[(size_t)row * HC + bn + ct * 16 + l15] = acc[rt][ct][r];
      }
    }
  }
}

// ---------------- attention logits: al_src/al_dst [N,H] --------------------
__global__ void logits_k(const float* __restrict__ hbuf,
                         const float* __restrict__ as_w,
                         const float* __restrict__ ad_w,
                         float* __restrict__ alsrc, float* __restrict__ aldst) {
  int idx = blockIdx.x * blockDim.x + threadIdx.x;
  if (idx >= NN * NHEAD) return;
  int n = idx >> 3, h = idx & 7;
  const float4* hp = (const float4*)(hbuf + (size_t)n * HC + h * 64);
  const float4* aw = (const float4*)(as_w + h * 64);
  const float4* dw = (const float4*)(ad_w + h * 64);
  float s = 0.f, d = 0.f;
#pragma unroll
  for (int c = 0; c < 16; c++) {
    float4 v = hp[c], a = aw[c], b = dw[c];
    s += v.x * a.x + v.y * a.y + v.z * a.z + v.w * a.w;
    d += v.x * b.x + v.y * b.y + v.z * b.z + v.w * b.w;
  }
  alsrc[idx] = s;
  aldst[idx] = d;
}

// ---------------- CSR build ------------------------------------------------
__global__ void count_k(const int* __restrict__ ei, int* __restrict__ counts) {
  int e = blockIdx.x * blockDim.x + threadIdx.x;
  if (e >= ETOT) return;
  int d = (e < EE) ? ei[EE + e] : (e - EE);
  atomicAdd(&counts[d], 1);
}

__global__ void scan_k(const int* __restrict__ counts, int* __restrict__ rowptr) {
  __shared__ int buf[1024];
  const int t = threadIdx.x;
  int base = 0;
  for (int c0 = 0; c0 < NN; c0 += 1024) {
    int i = c0 + t;
    int v = (i < NN) ? counts[i] : 0;
    buf[t] = v;
    __syncthreads();
    for (int off = 1; off < 1024; off <<= 1) {
      int tv = (t >= off) ? buf[t - off] : 0;
      __syncthreads();
      buf[t] += tv;
      __syncthreads();
    }
    if (i < NN) rowptr[i + 1] = base + buf[t];
    base += buf[1023];
    __syncthreads();
  }
  if (t == 0) rowptr[0] = 0;
}

// CSR fill: store src node and log2(edge weight) in CSR order
__global__ void fill_k(const int* __restrict__ ei, const void* __restrict__ ew,
                       const int* __restrict__ flag, const int* __restrict__ rowptr,
                       int* __restrict__ cursor, int* __restrict__ esrc,
                       float* __restrict__ elw) {
  int e = blockIdx.x * blockDim.x + threadIdx.x;
  if (e >= ETOT) return;
  int s, d;
  float lw;
  if (e < EE) {
    s = ei[e];
    d = ei[EE + e];
    float w = (*flag) ? __bfloat162float(((const __hip_bfloat16*)ew)[e])
                      : ((const float*)ew)[e];
    lw = log2f(w);
  } else {
    s = d = e - EE;
    lw = 0.f;
  }
  int pos = atomicAdd(&cursor[d], 1);
  int idx = rowptr[d] + pos;
  esrc[idx] = s;
  elw[idx] = lw;
}

// ---------------- per-node segment softmax stats (max, denom) --------------
__global__ __launch_bounds__(64) void softmax_k(const float* __restrict__ alsrc,
                                                const float* __restrict__ aldst,
                                                const int* __restrict__ rowptr,
                                                const int* __restrict__ esrc,
                                                const float* __restrict__ elw,
                                                float* __restrict__ amax,
                                                float* __restrict__ denom) {
  const int n = blockIdx.x, lane = threadIdx.x;
  const int h = lane & 7, eo = lane >> 3;
  const int beg = rowptr[n], end = rowptr[n + 1];
  const float aln = aldst[n * NHEAD + h];
  float m = -1e30f;
  for (int base = beg; base < end; base += 8) {
    int e = base + eo;
    if (e < end) {
      float a = alsrc[esrc[e] * NHEAD + h] + aln;
      a = (a > 0.f) ? a : NEG * a;
      a += elw[e];
      m = fmaxf(m, a);
    }
  }
  m = fmaxf(m, __shfl_xor(m, 8));
  m = fmaxf(m, __shfl_xor(m, 16));
  m = fmaxf(m, __shfl_xor(m, 32));
  float sum = 0.f;
  for (int base = beg; base < end; base += 8) {
    int e = base + eo;
    if (e < end) {
      float a = alsrc[esrc[e] * NHEAD + h] + aln;
      a = (a > 0.f) ? a : NEG * a;
      a += elw[e];
      sum += expf(a - m);
    }
  }
  sum += __shfl_xor(sum, 8);
  sum += __shfl_xor(sum, 16);
  sum += __shfl_xor(sum, 32);
  if (lane < 8) {
    amax[n * NHEAD + lane] = m;
    denom[n * NHEAD + lane] = sum;
  }
}

// ---------------- fused softmax-weight + aggregation -----------------------
template <bool RELU, bool FINAL>
__global__ __launch_bounds__(256) void agg_k(const float* __restrict__ hbuf,
                                             const float* __restrict__ alsrc,
                                             const float* __restrict__ aldst,
                                             const float* __restrict__ amax,
                                             const float* __restrict__ denom,
                                             const int* __restrict__ rowptr,
                                             const int* __restrict__ esrc,
                                             const float* __restrict__ elw,
                                             const float* __restrict__ bias,
                                             __hip_bfloat16* __restrict__ outB,
                                             float* __restrict__ outF,
                                             const int* __restrict__ flag) {
  const int n = blockIdx.x, t = threadIdx.x;
  __shared__ float sw[32 * NHEAD];
  __shared__ int ss[32];
  __shared__ float sm[NHEAD], sd[NHEAD], sal[NHEAD];
  if (t < NHEAD) {
    sm[t] = amax[n * NHEAD + t];
    sd[t] = denom[n * NHEAD + t];
    sal[t] = aldst[n * NHEAD + t];
  }
  __syncthreads();
  const int h = t & 7, eslot = t >> 3;
  const int h0 = t >> 6, h1 = (t >> 6) + 4;
  const float aln_h = sal[h];
  const float m_h = sm[h];
  float acc0 = 0.f, acc1 = 0.f;
  const int beg = rowptr[n], end = rowptr[n + 1];
  for (int base = beg; base < end; base += 32) {
    int cnt = min(32, end - base);
    if (eslot < cnt) {
      int e = base + eslot;
      int s = esrc[e];
      float a = alsrc[s * NHEAD + h] + aln_h;
      a = (a > 0.f) ? a : NEG * a;
      a += elw[e];
      sw[eslot * NHEAD + h] = expf(a - m_h);
      if (h == 0) ss[eslot] = s;
    }
    __syncthreads();
    for (int i = 0; i < cnt; i++) {
      int s = ss[i];
      const float* hp = hbuf + (size_t)s * HC;
      acc0 += sw[i * NHEAD + h0] * hp[t];
      acc1 += sw[i * NHEAD + h1] * hp[t + 256];
    }
    __syncthreads();
  }
  float v0 = acc0 / sd[h0] + bias[t];
  float v1 = acc1 / sd[h1] + bias[t + 256];
  if (RELU) {
    v0 = fmaxf(v0, 0.f);
    v1 = fmaxf(v1, 0.f);
  }
  size_t o0 = (size_t)n * HC + t;
  if (FINAL && !(*flag)) {
    outF[o0] = v0;
    outF[o0 + 256] = v1;
  } else {
    outB[o0] = __float2bfloat16(v0);
    outB[o0 + 256] = __float2bfloat16(v1);
  }
}

// ---------------- workspace layout -----------------------------------------
static constexpr size_t algn(size_t x) { return (x + 255) & ~(size_t)255; }
static constexpr size_t oFlag = 0;
static constexpr size_t oXB = algn(oFlag + 256);
static constexpr size_t oW1B = algn(oXB + (size_t)NN * CIN * 2);
static constexpr size_t oW2B = algn(oW1B + (size_t)CIN * HC * 2);
static constexpr size_t oAtt = algn(oW2B + (size_t)HC * HC * 2);
static constexpr size_t oH = algn(oAtt + 6 * 512 * 4);
static constexpr size_t oO1B = algn(oH + (size_t)NN * HC * 4);
static constexpr size_t oAS = algn(oO1B + (size_t)NN * HC * 2);
static constexpr size_t oAD = algn(oAS + (size_t)NN * NHEAD * 4);
static constexpr size_t oMax = algn(oAD + (size_t)NN * NHEAD * 4);
static constexpr size_t oDen = algn(oMax + (size_t)NN * NHEAD * 4);
static constexpr size_t oRP = algn(oDen + (size_t)NN * NHEAD * 4);
static constexpr size_t oCur = algn(oRP + (size_t)(NN + 1) * 4);
static constexpr size_t oESrc = algn(oCur + (size_t)NN * 4);
static constexpr size_t oELW = algn(oESrc + (size_t)ETOT * 4);

extern "C" void kernel_launch(void* const* d_in, const int* in_sizes, int n_in,
                              void* d_out, int out_size, void* d_ws, size_t ws_size,
                              hipStream_t stream) {
  (void)in_sizes; (void)n_in; (void)out_size; (void)ws_size;
  const int* ei = (const int*)d_in[1];

  char* ws = (char*)d_ws;
  int* flag = (int*)(ws + oFlag);
  u16* xb = (u16*)(ws + oXB);
  u16* w1b = (u16*)(ws + oW1B);
  u16* w2b = (u16*)(ws + oW2B);
  float* attf = (float*)(ws + oAtt);
  float* as1f = attf, *ad1f = attf + 512, *b1f = attf + 1024;
  float* as2f = attf + 1536, *ad2f = attf + 2048, *b2f = attf + 2560;
  float* hbuf = (float*)(ws + oH);
  u16* o1b = (u16*)(ws + oO1B);
  float* alsrc = (float*)(ws + oAS);
  float* aldst = (float*)(ws + oAD);
  float* amax = (float*)(ws + oMax);
  float* denom = (float*)(ws + oDen);
  int* rowptr = (int*)(ws + oRP);
  int* cursor = (int*)(ws + oCur);
  int* esrc = (int*)(ws + oESrc);
  float* elw = (float*)(ws + oELW);

  const int eb = (ETOT + 255) / 256;

  // ---- dtype detect + input conversion ----
  detect_k<<<1, 64, 0, stream>>>((const u16*)d_in[0], flag);
  cvtb_k<<<(NN * CIN + 255) / 256, 256, 0, stream>>>(d_in[0], xb, NN * CIN, flag);
  cvtb_k<<<(CIN * HC + 255) / 256, 256, 0, stream>>>(d_in[3], w1b, CIN * HC, flag);
  cvtb_k<<<(HC * HC + 255) / 256, 256, 0, stream>>>(d_in[7], w2b, HC * HC, flag);
  cvt6_k<<<(6 * 512 + 255) / 256, 256, 0, stream>>>(d_in[4], d_in[5], d_in[6],
                                                    d_in[8], d_in[9], d_in[10],
                                                    attf, flag);

  // ---- CSR build (shared by both layers) ----
  hipMemsetAsync(cursor, 0, (size_t)NN * 4, stream);
  count_k<<<eb, 256, 0, stream>>>(ei, cursor);
  scan_k<<<1, 1024, 0, stream>>>(cursor, rowptr);
  hipMemsetAsync(cursor, 0, (size_t)NN * 4, stream);
  fill_k<<<eb, 256, 0, stream>>>(ei, d_in[2], flag, rowptr, cursor, esrc, elw);

  // ---- layer 1 ----
  gemm_mfma<<<dim3(HC / BN, (NN + BM - 1) / BM), 256, 0, stream>>>(xb, w1b, hbuf, NN, CIN);
  logits_k<<<(NN * NHEAD + 255) / 256, 256, 0, stream>>>(hbuf, as1f, ad1f, alsrc, aldst);
  softmax_k<<<NN, 64, 0, stream>>>(alsrc, aldst, rowptr, esrc, elw, amax, denom);
  agg_k<true, false><<<NN, 256, 0, stream>>>(hbuf, alsrc, aldst, amax, denom, rowptr,
                                             esrc, elw, b1f, (__hip_bfloat16*)o1b,
                                             nullptr, flag);

  // ---- layer 2 ----
  gemm_mfma<<<dim3(HC / BN, (NN + BM - 1) / BM), 256, 0, stream>>>(o1b, w2b, hbuf, NN, HC);
  logits_k<<<(NN * NHEAD + 255) / 256, 256, 0, stream>>>(hbuf, as2f, ad2f, alsrc, aldst);
  softmax_k<<<NN, 64, 0, stream>>>(alsrc, aldst, rowptr, esrc, elw, amax, denom);
  agg_k<false, true><<<NN, 256, 0, stream>>>(hbuf, alsrc, aldst, amax, denom, rowptr,
                                             esrc, elw, b2f, (__hip_bfloat16*)d_out,
                                             (float*)d_out, flag);
}

// Round 5
// 318.057 us; speedup vs baseline: 3.6839x; 1.2910x over previous
//
#include <hip/hip_runtime.h>
#include <hip/hip_bf16.h>

#define NN 10000
#define EE 320000
#define ETOT (EE + NN)
#define CIN 256
#define HC 512
#define NHEAD 8
#define NEG 0.2f

using bf16x8 = __attribute__((ext_vector_type(8))) short;
using f32x4 = __attribute__((ext_vector_type(4))) float;
typedef unsigned short u16;
typedef unsigned int u32;

__device__ __forceinline__ u16 f2bf(float f) {
  __hip_bfloat16 b = __float2bfloat16(f);
  return *(u16*)&b;
}
__device__ __forceinline__ float bflo(u32 p) { return __uint_as_float(p << 16); }
__device__ __forceinline__ float bfhi(u32 p) { return __uint_as_float(p & 0xFFFF0000u); }

// ---------------- dtype detect: bf16 vs fp32 float inputs -------------------
__global__ void detect_k(const u16* __restrict__ x, int* __restrict__ flag) {
  if (threadIdx.x == 0 && blockIdx.x == 0) {
    int isbf16 = 1;
    for (int i = 0; i < 512; i++) {
      unsigned e = (x[i] >> 7) & 0xFFu;
      if (e >= 0xC8u) { isbf16 = 0; break; }
    }
    *flag = isbf16;
  }
}

// ---------------- fused input conversion (x, W1, W2 -> bf16; att -> fp32) ---
#define SX (NN * CIN)
#define SW1 (CIN * HC)
#define SW2 (HC * HC)
#define SATT (6 * 512)
__global__ void cvtall_k(const void* __restrict__ x, const void* __restrict__ w1,
                         const void* __restrict__ w2,
                         const void* a0, const void* a1, const void* a2,
                         const void* a3, const void* a4, const void* a5,
                         u16* __restrict__ xb, u16* __restrict__ w1b,
                         u16* __restrict__ w2b, float* __restrict__ attf,
                         const int* __restrict__ flag) {
  int i = blockIdx.x * blockDim.x + threadIdx.x;
  const bool bf = (*flag != 0);
  if (i < SX) {
    xb[i] = bf ? ((const u16*)x)[i] : f2bf(((const float*)x)[i]);
  } else if (i < SX + SW1) {
    int j = i - SX;
    w1b[j] = bf ? ((const u16*)w1)[j] : f2bf(((const float*)w1)[j]);
  } else if (i < SX + SW1 + SW2) {
    int j = i - SX - SW1;
    w2b[j] = bf ? ((const u16*)w2)[j] : f2bf(((const float*)w2)[j]);
  } else if (i < SX + SW1 + SW2 + SATT) {
    int j = i - SX - SW1 - SW2;
    const void* ps[6] = {a0, a1, a2, a3, a4, a5};
    const void* p = ps[j >> 9];
    int k = j & 511;
    attf[j] = bf ? __bfloat162float(((const __hip_bfloat16*)p)[k])
                 : ((const float*)p)[k];
  }
}

// ---------------- MFMA GEMM: C[M,512] = A[M,K] @ B[K,512], bf16 in fp32 out -
#define BM 128
#define BN 64
#define BK 32
#define APAD 40
#define BPAD 40

__global__ __launch_bounds__(256) void gemm_mfma(const u16* __restrict__ A,
                                                 const u16* __restrict__ B,
                                                 float* __restrict__ C,
                                                 int M, int K) {
  __shared__ u16 As[BM * APAD];
  __shared__ u16 Bs[BN * BPAD];
  const int bm = blockIdx.y * BM, bn = blockIdx.x * BN;
  const int t = threadIdx.x;
  const int wave = t >> 6, lane = t & 63;
  const int l15 = lane & 15, quad = lane >> 4;
  f32x4 acc[2][4] = {};
  for (int k0 = 0; k0 < K; k0 += BK) {
    // stage A: 128 rows x 32 cols bf16 (64 B/row): thread t -> row t>>1,
    // 32-byte half t&1 (two int4s).
    {
      int row = t >> 1, half = t & 1;
      int gr = bm + row;
      int4 v0 = make_int4(0, 0, 0, 0), v1 = v0;
      if (gr < M) {
        const int4* gp = (const int4*)(A + (size_t)gr * K + k0 + half * 16);
        v0 = gp[0];
        v1 = gp[1];
      }
      int4* lp = (int4*)(As + row * APAD + half * 16);
      lp[0] = v0;
      lp[1] = v1;
    }
    // stage B transposed (n-major): k-pair packed u32 writes
    {
      int n = t & 63;
#pragma unroll
      for (int j = 0; j < 4; j++) {
        int kp = (t >> 6) + j * 4;  // 0..15
        int k = kp * 2;
        u16 b0 = B[(size_t)(k0 + k) * HC + bn + n];
        u16 b1 = B[(size_t)(k0 + k + 1) * HC + bn + n];
        *(u32*)(Bs + n * BPAD + k) = (u32)b0 | ((u32)b1 << 16);
      }
    }
    __syncthreads();
    bf16x8 af[2], bfr[4];
#pragma unroll
    for (int rt = 0; rt < 2; rt++)
      af[rt] = *(const bf16x8*)(As + (wave * 32 + rt * 16 + l15) * APAD + quad * 8);
#pragma unroll
    for (int ct = 0; ct < 4; ct++)
      bfr[ct] = *(const bf16x8*)(Bs + (ct * 16 + l15) * BPAD + quad * 8);
#pragma unroll
    for (int rt = 0; rt < 2; rt++)
#pragma unroll
      for (int ct = 0; ct < 4; ct++)
        acc[rt][ct] = __builtin_amdgcn_mfma_f32_16x16x32_bf16(af[rt], bfr[ct],
                                                              acc[rt][ct], 0, 0, 0);
    __syncthreads();
  }
  // epilogue: D row = quad*4 + reg, col = lane&15
#pragma unroll
  for (int rt = 0; rt < 2; rt++) {
#pragma unroll
    for (int r = 0; r < 4; r++) {
      int row = bm + wave * 32 + rt * 16 + quad * 4 + r;
      if (row < M) {
#pragma unroll
        for (int ct = 0; ct < 4; ct++)
          C[(size_t)row * HC + bn + ct * 16 + l15] = acc[rt][ct][r];
      }
    }
  }
}

// ---------------- attention logits + bf16 h copy ---------------------------
__global__ void logits_k(const float* __restrict__ hbuf,
                         const float* __restrict__ as_w,
                         const float* __restrict__ ad_w,
                         float* __restrict__ alsrc, float* __restrict__ aldst,
                         u16* __restrict__ hb) {
  int idx = blockIdx.x * blockDim.x + threadIdx.x;
  if (idx >= NN * NHEAD) return;
  int n = idx >> 3, h = idx & 7;
  const float4* hp = (const float4*)(hbuf + (size_t)n * HC + h * 64);
  const float4* aw = (const float4*)(as_w + h * 64);
  const float4* dw = (const float4*)(ad_w + h * 64);
  u32* hbp = (u32*)(hb + (size_t)n * HC + h * 64);
  float s = 0.f, d = 0.f;
#pragma unroll
  for (int c = 0; c < 16; c++) {
    float4 v = hp[c], a = aw[c], b = dw[c];
    s += v.x * a.x + v.y * a.y + v.z * a.z + v.w * a.w;
    d += v.x * b.x + v.y * b.y + v.z * b.z + v.w * b.w;
    hbp[c * 2] = (u32)f2bf(v.x) | ((u32)f2bf(v.y) << 16);
    hbp[c * 2 + 1] = (u32)f2bf(v.z) | ((u32)f2bf(v.w) << 16);
  }
  alsrc[idx] = s;
  aldst[idx] = d;
}

// ---------------- CSR build ------------------------------------------------
__global__ void count_k(const int* __restrict__ ei, int* __restrict__ counts) {
  int e = blockIdx.x * blockDim.x + threadIdx.x;
  if (e >= ETOT) return;
  int d = (e < EE) ? ei[EE + e] : (e - EE);
  atomicAdd(&counts[d], 1);
}

// 1024 threads; thread t serially handles nodes [t*10, t*10+10)
__global__ __launch_bounds__(1024) void scan_k(const int* __restrict__ counts,
                                               int* __restrict__ rowptr) {
  __shared__ int buf[1024];
  const int t = threadIdx.x;
  int loc[10];
  int s = 0;
#pragma unroll
  for (int j = 0; j < 10; j++) {
    int i = t * 10 + j;
    s += (i < NN) ? counts[i] : 0;
    loc[j] = s;
  }
  buf[t] = s;
  __syncthreads();
  for (int off = 1; off < 1024; off <<= 1) {
    int v = (t >= off) ? buf[t - off] : 0;
    __syncthreads();
    buf[t] += v;
    __syncthreads();
  }
  int base = (t > 0) ? buf[t - 1] : 0;
#pragma unroll
  for (int j = 0; j < 10; j++) {
    int i = t * 10 + j;
    if (i < NN) rowptr[i + 1] = base + loc[j];
  }
  if (t == 0) rowptr[0] = 0;
}

// CSR fill: store src node and log2(edge weight) in CSR order
__global__ void fill_k(const int* __restrict__ ei, const void* __restrict__ ew,
                       const int* __restrict__ flag, const int* __restrict__ rowptr,
                       int* __restrict__ cursor, int* __restrict__ esrc,
                       float* __restrict__ elw) {
  int e = blockIdx.x * blockDim.x + threadIdx.x;
  if (e >= ETOT) return;
  int s, d;
  float lw;
  if (e < EE) {
    s = ei[e];
    d = ei[EE + e];
    float w = (*flag) ? __bfloat162float(((const __hip_bfloat16*)ew)[e])
                      : ((const float*)ew)[e];
    lw = log2f(w);
  } else {
    s = d = e - EE;
    lw = 0.f;
  }
  int pos = atomicAdd(&cursor[d], 1);
  int idx = rowptr[d] + pos;
  esrc[idx] = s;
  elw[idx] = lw;
}

// ------- fused segment softmax (max+denom in-block) + aggregation ----------
// thread t: softmax passes use (h = t&7, slot = t>>3); aggregation uses
// channels {2t, 2t+1}, head hh = t>>5. h rows gathered as packed bf16 pairs.
template <bool RELU, bool FINAL>
__global__ __launch_bounds__(256) void agg_k(const u16* __restrict__ hb,
                                             const float* __restrict__ alsrc,
                                             const float* __restrict__ aldst,
                                             const int* __restrict__ rowptr,
                                             const int* __restrict__ esrc,
                                             const float* __restrict__ elw,
                                             const float* __restrict__ bias,
                                             u32* __restrict__ outB,
                                             float* __restrict__ outF,
                                             const int* __restrict__ flag) {
  const int n = blockIdx.x, t = threadIdx.x;
  __shared__ float red[256];
  __shared__ float sw[32 * NHEAD];
  __shared__ int ss[32];
  __shared__ float sm[NHEAD], sd[NHEAD], sal[NHEAD];
  if (t < NHEAD) sal[t] = aldst[n * NHEAD + t];
  __syncthreads();
  const int h = t & 7, eo = t >> 3;
  const int beg = rowptr[n], end = rowptr[n + 1];
  const float aln = sal[h];
  // pass A1: per-head max
  float m = -1e30f;
  for (int e = beg + eo; e < end; e += 32) {
    float a = alsrc[esrc[e] * NHEAD + h] + aln;
    a = (a > 0.f) ? a : NEG * a;
    a += elw[e];
    m = fmaxf(m, a);
  }
  red[t] = m;
  __syncthreads();
  for (int off = 128; off >= 8; off >>= 1) {
    if (t < off) red[t] = fmaxf(red[t], red[t + off]);
    __syncthreads();
  }
  if (t < NHEAD) sm[t] = red[t];
  __syncthreads();
  // pass A2: per-head denom
  const float mh = sm[h];
  float sum = 0.f;
  for (int e = beg + eo; e < end; e += 32) {
    float a = alsrc[esrc[e] * NHEAD + h] + aln;
    a = (a > 0.f) ? a : NEG * a;
    a += elw[e];
    sum += expf(a - mh);
  }
  red[t] = sum;
  __syncthreads();
  for (int off = 128; off >= 8; off >>= 1) {
    if (t < off) red[t] += red[t + off];
    __syncthreads();
  }
  if (t < NHEAD) sd[t] = red[t];
  __syncthreads();
  // pass B: weights per 32-edge chunk + gather-aggregate
  const int hh = t >> 5;
  float acc0 = 0.f, acc1 = 0.f;
  for (int base = beg; base < end; base += 32) {
    int cnt = min(32, end - base);
    if (eo < cnt) {
      int e = base + eo;
      int s = esrc[e];
      float a = alsrc[s * NHEAD + h] + aln;
      a = (a > 0.f) ? a : NEG * a;
      a += elw[e];
      sw[eo * NHEAD + h] = expf(a - mh);
      if (h == 0) ss[eo] = s;
    }
    __syncthreads();
    for (int i = 0; i < cnt; i++) {
      int s = ss[i];
      u32 p = *(const u32*)(hb + (size_t)s * HC + 2 * t);
      float w = sw[i * NHEAD + hh];
      acc0 += w * bflo(p);
      acc1 += w * bfhi(p);
    }
    __syncthreads();
  }
  const float inv = 1.f / sd[hh];
  float v0 = acc0 * inv + bias[2 * t];
  float v1 = acc1 * inv + bias[2 * t + 1];
  if (RELU) {
    v0 = fmaxf(v0, 0.f);
    v1 = fmaxf(v1, 0.f);
  }
  if (FINAL && !(*flag)) {
    outF[(size_t)n * HC + 2 * t] = v0;
    outF[(size_t)n * HC + 2 * t + 1] = v1;
  } else {
    outB[(size_t)n * (HC / 2) + t] = (u32)f2bf(v0) | ((u32)f2bf(v1) << 16);
  }
}

// ---------------- workspace layout -----------------------------------------
static constexpr size_t algn(size_t x) { return (x + 255) & ~(size_t)255; }
static constexpr size_t oFlag = 0;
static constexpr size_t oXB = algn(oFlag + 256);
static constexpr size_t oW1B = algn(oXB + (size_t)SX * 2);
static constexpr size_t oW2B = algn(oW1B + (size_t)SW1 * 2);
static constexpr size_t oAtt = algn(oW2B + (size_t)SW2 * 2);
static constexpr size_t oH = algn(oAtt + (size_t)SATT * 4);      // fp32 h
static constexpr size_t oHB = algn(oH + (size_t)NN * HC * 4);    // bf16 h
static constexpr size_t oO1B = algn(oHB + (size_t)NN * HC * 2);  // bf16 o1
static constexpr size_t oAS = algn(oO1B + (size_t)NN * HC * 2);
static constexpr size_t oAD = algn(oAS + (size_t)NN * NHEAD * 4);
static constexpr size_t oRP = algn(oAD + (size_t)NN * NHEAD * 4);
static constexpr size_t oCur = algn(oRP + (size_t)(NN + 1) * 4);
static constexpr size_t oESrc = algn(oCur + (size_t)NN * 4);
static constexpr size_t oELW = algn(oESrc + (size_t)ETOT * 4);

extern "C" void kernel_launch(void* const* d_in, const int* in_sizes, int n_in,
                              void* d_out, int out_size, void* d_ws, size_t ws_size,
                              hipStream_t stream) {
  (void)in_sizes; (void)n_in; (void)out_size; (void)ws_size;
  const int* ei = (const int*)d_in[1];

  char* ws = (char*)d_ws;
  int* flag = (int*)(ws + oFlag);
  u16* xb = (u16*)(ws + oXB);
  u16* w1b = (u16*)(ws + oW1B);
  u16* w2b = (u16*)(ws + oW2B);
  float* attf = (float*)(ws + oAtt);
  float* as1f = attf, *ad1f = attf + 512, *b1f = attf + 1024;
  float* as2f = attf + 1536, *ad2f = attf + 2048, *b2f = attf + 2560;
  float* hbuf = (float*)(ws + oH);
  u16* hb = (u16*)(ws + oHB);
  u16* o1b = (u16*)(ws + oO1B);
  float* alsrc = (float*)(ws + oAS);
  float* aldst = (float*)(ws + oAD);
  int* rowptr = (int*)(ws + oRP);
  int* cursor = (int*)(ws + oCur);
  int* esrc = (int*)(ws + oESrc);
  float* elw = (float*)(ws + oELW);

  const int eb = (ETOT + 255) / 256;
  const int cvb = (SX + SW1 + SW2 + SATT + 255) / 256;

  // ---- dtype detect + fused input conversion ----
  detect_k<<<1, 64, 0, stream>>>((const u16*)d_in[0], flag);
  cvtall_k<<<cvb, 256, 0, stream>>>(d_in[0], d_in[3], d_in[7],
                                    d_in[4], d_in[5], d_in[6],
                                    d_in[8], d_in[9], d_in[10],
                                    xb, w1b, w2b, attf, flag);

  // ---- CSR build (shared by both layers) ----
  hipMemsetAsync(cursor, 0, (size_t)NN * 4, stream);
  count_k<<<eb, 256, 0, stream>>>(ei, cursor);
  scan_k<<<1, 1024, 0, stream>>>(cursor, rowptr);
  hipMemsetAsync(cursor, 0, (size_t)NN * 4, stream);
  fill_k<<<eb, 256, 0, stream>>>(ei, d_in[2], flag, rowptr, cursor, esrc, elw);

  // ---- layer 1 ----
  gemm_mfma<<<dim3(HC / BN, (NN + BM - 1) / BM), 256, 0, stream>>>(xb, w1b, hbuf, NN, CIN);
  logits_k<<<(NN * NHEAD + 255) / 256, 256, 0, stream>>>(hbuf, as1f, ad1f, alsrc, aldst, hb);
  agg_k<true, false><<<NN, 256, 0, stream>>>(hb, alsrc, aldst, rowptr, esrc, elw,
                                             b1f, (u32*)o1b, nullptr, flag);

  // ---- layer 2 ----
  gemm_mfma<<<dim3(HC / BN, (NN + BM - 1) / BM), 256, 0, stream>>>(o1b, w2b, hbuf, NN, HC);
  logits_k<<<(NN * NHEAD + 255) / 256, 256, 0, stream>>>(hbuf, as2f, ad2f, alsrc, aldst, hb);
  agg_k<false, true><<<NN, 256, 0, stream>>>(hb, alsrc, aldst, rowptr, esrc, elw,
                                             b2f, (u32*)d_out, (float*)d_out, flag);
}

// Round 6
// 271.184 us; speedup vs baseline: 4.3207x; 1.1728x over previous
//
#include <hip/hip_runtime.h>
#include <hip/hip_bf16.h>

#define NN 10000
#define EE 320000
#define ETOT (EE + NN)
#define CIN 256
#define HC 512
#define NHEAD 8
#define NEG 0.2f

#define SX (NN * CIN)
#define SW1 (CIN * HC)
#define SW2 (HC * HC)
#define SATT (6 * 512)

using bf16x8 = __attribute__((ext_vector_type(8))) short;
using f32x4 = __attribute__((ext_vector_type(4))) float;
typedef unsigned short u16;
typedef unsigned int u32;

__device__ __forceinline__ u16 f2bf(float f) {
  __hip_bfloat16 b = __float2bfloat16(f);
  return *(u16*)&b;
}
__device__ __forceinline__ float bflo(u32 p) { return __uint_as_float(p << 16); }
__device__ __forceinline__ float bfhi(u32 p) { return __uint_as_float(p & 0xFFFF0000u); }

// ---- zero counts + dtype detect (bf16 vs fp32), one dispatch ---------------
__global__ void zdetect_k(const u16* __restrict__ x, int* __restrict__ flag,
                          int* __restrict__ counts) {
  int i = blockIdx.x * blockDim.x + threadIdx.x;
  if (i < NN) counts[i] = 0;
  if (blockIdx.x == 0 && threadIdx.x < 64) {
    int bad = 0;
    for (int j = threadIdx.x; j < 512; j += 64) {
      unsigned e = (x[j] >> 7) & 0xFFu;
      if (e >= 0xC8u) bad = 1;
    }
    unsigned long long b = __ballot(bad);
    if (threadIdx.x == 0) *flag = (b == 0ull) ? 1 : 0;
  }
}

// ---- fused: convert x->bf16, att vecs->fp32, AND count dst degrees ---------
__global__ void cvt_count_k(const void* __restrict__ x,
                            const void* a0, const void* a1, const void* a2,
                            const void* a3, const void* a4, const void* a5,
                            const int* __restrict__ ei,
                            u16* __restrict__ xb, float* __restrict__ attf,
                            int* __restrict__ counts, const int* __restrict__ flag) {
  int i = blockIdx.x * blockDim.x + threadIdx.x;
  const bool bf = (*flag != 0);
  if (i < SX) {
    xb[i] = bf ? ((const u16*)x)[i] : f2bf(((const float*)x)[i]);
  } else if (i < SX + SATT) {
    int j = i - SX;
    const void* ps[6] = {a0, a1, a2, a3, a4, a5};
    const void* p = ps[j >> 9];
    int k = j & 511;
    attf[j] = bf ? __bfloat162float(((const __hip_bfloat16*)p)[k])
                 : ((const float*)p)[k];
  }
  if (i < ETOT) {
    int d = (i < EE) ? ei[EE + i] : (i - EE);
    atomicAdd(&counts[d], 1);
  }
}

// ---- transpose W1 [256,512] and W2 [512,512] -> [512][K] bf16 --------------
__global__ __launch_bounds__(256) void wtrans_k(const void* __restrict__ w1,
                                                const void* __restrict__ w2,
                                                u16* __restrict__ w1t,
                                                u16* __restrict__ w2t,
                                                const int* __restrict__ flag) {
  __shared__ u16 tile[64][72];
  int b = blockIdx.x;
  const void* src;
  u16* dst;
  int K, tk, tn;
  if (b < 32) { src = w1; dst = w1t; K = CIN; tk = (b >> 3) * 64; tn = (b & 7) * 64; }
  else { b -= 32; src = w2; dst = w2t; K = HC; tk = (b >> 3) * 64; tn = (b & 7) * 64; }
  const bool bf = (*flag != 0);
  const int t = threadIdx.x;
  const int r = t >> 2, cb = (t & 3) * 16;
  if (bf) {
    const u16* s = (const u16*)src + (size_t)(tk + r) * HC + tn + cb;
    *(int4*)&tile[r][cb] = ((const int4*)s)[0];
    *(int4*)&tile[r][cb + 8] = ((const int4*)s)[1];
  } else {
    const float* s = (const float*)src + (size_t)(tk + r) * HC + tn + cb;
#pragma unroll
    for (int j = 0; j < 16; j++) tile[r][cb + j] = f2bf(s[j]);
  }
  __syncthreads();
  union { u16 o[16]; int4 v[2]; } u;
#pragma unroll
  for (int j = 0; j < 16; j++) u.o[j] = tile[cb + j][r];
  int4* dp = (int4*)(dst + (size_t)(tn + r) * K + tk + cb);
  dp[0] = u.v[0];
  dp[1] = u.v[1];
}

// ---- exclusive scan: rowptr[N+1] + wcur (working cursors = starts) ---------
__global__ __launch_bounds__(1024) void scan_k(const int* __restrict__ counts,
                                               int* __restrict__ rowptr,
                                               int* __restrict__ wcur) {
  __shared__ int buf[1024];
  const int t = threadIdx.x;
  int loc[10];
  int s = 0;
#pragma unroll
  for (int j = 0; j < 10; j++) {
    int i = t * 10 + j;
    s += (i < NN) ? counts[i] : 0;
    loc[j] = s;
  }
  buf[t] = s;
  __syncthreads();
  for (int off = 1; off < 1024; off <<= 1) {
    int v = (t >= off) ? buf[t - off] : 0;
    __syncthreads();
    buf[t] += v;
    __syncthreads();
  }
  int base = (t > 0) ? buf[t - 1] : 0;
  int prev = 0;
#pragma unroll
  for (int j = 0; j < 10; j++) {
    int i = t * 10 + j;
    if (i < NN) {
      rowptr[i + 1] = base + loc[j];
      wcur[i] = base + prev;
    }
    prev = loc[j];
  }
  if (t == 0) rowptr[0] = 0;
}

// ---- CSR fill via wcur (no second memset, no rowptr read) ------------------
__global__ void fill_k(const int* __restrict__ ei, const void* __restrict__ ew,
                       const int* __restrict__ flag, int* __restrict__ wcur,
                       int* __restrict__ esrc, float* __restrict__ elw) {
  int e = blockIdx.x * blockDim.x + threadIdx.x;
  if (e >= ETOT) return;
  int s, d;
  float lw;
  if (e < EE) {
    s = ei[e];
    d = ei[EE + e];
    float w = (*flag) ? __bfloat162float(((const __hip_bfloat16*)ew)[e])
                      : ((const float*)ew)[e];
    lw = log2f(w);
  } else {
    s = d = e - EE;
    lw = 0.f;
  }
  int pos = atomicAdd(&wcur[d], 1);
  esrc[pos] = s;
  elw[pos] = lw;
}

// ---- MFMA GEMM + fused logits: hb(bf16) = A@W^T-tiles; al_src/al_dst -------
// grid (8, ceil(M/128)); blockIdx.x == head (BN = 64 = HID).
#define BM 128
#define BN 64
#define BK 32
#define APAD 40
#define BPAD 40

__global__ __launch_bounds__(256) void gemm_mfma(const u16* __restrict__ A,
                                                 const u16* __restrict__ Wt,
                                                 const float* __restrict__ as_w,
                                                 const float* __restrict__ ad_w,
                                                 u16* __restrict__ hb,
                                                 float* __restrict__ alsrc,
                                                 float* __restrict__ aldst,
                                                 int M, int K) {
  __shared__ u16 As[BM * APAD];
  __shared__ u16 Bs[BN * BPAD];
  const int head = blockIdx.x;
  const int bm = blockIdx.y * BM, bn = head * BN;
  const int t = threadIdx.x;
  const int wave = t >> 6, lane = t & 63;
  const int l15 = lane & 15, quad = lane >> 4;
  f32x4 acc[2][4] = {};
  for (int k0 = 0; k0 < K; k0 += BK) {
    // stage A: 128 rows x 32 k (64 B/row); thread t -> row t>>1, 32B half t&1
    {
      int row = t >> 1, half = t & 1;
      int gr = bm + row;
      int4 v0 = make_int4(0, 0, 0, 0), v1 = v0;
      if (gr < M) {
        const int4* gp = (const int4*)(A + (size_t)gr * K + k0 + half * 16);
        v0 = gp[0];
        v1 = gp[1];
      }
      int4* lp = (int4*)(As + row * APAD + half * 16);
      lp[0] = v0;
      lp[1] = v1;
    }
    // stage B from transposed W [n][K]: thread t -> n-row t>>2, 16B quarter t&3
    {
      int row = t >> 2, kq = (t & 3) * 8;
      *(int4*)(Bs + row * BPAD + kq) =
          *(const int4*)(Wt + (size_t)(bn + row) * K + k0 + kq);
    }
    __syncthreads();
    bf16x8 af[2], bfr[4];
#pragma unroll
    for (int rt = 0; rt < 2; rt++)
      af[rt] = *(const bf16x8*)(As + (wave * 32 + rt * 16 + l15) * APAD + quad * 8);
#pragma unroll
    for (int ct = 0; ct < 4; ct++)
      bfr[ct] = *(const bf16x8*)(Bs + (ct * 16 + l15) * BPAD + quad * 8);
#pragma unroll
    for (int rt = 0; rt < 2; rt++)
#pragma unroll
      for (int ct = 0; ct < 4; ct++)
        acc[rt][ct] = __builtin_amdgcn_mfma_f32_16x16x32_bf16(af[rt], bfr[ct],
                                                              acc[rt][ct], 0, 0, 0);
    __syncthreads();
  }
  // epilogue: bf16 h store + per-row attention logits (fp32 accs).
  float asw[4], adw[4];
#pragma unroll
  for (int ct = 0; ct < 4; ct++) {
    asw[ct] = as_w[head * 64 + ct * 16 + l15];
    adw[ct] = ad_w[head * 64 + ct * 16 + l15];
  }
#pragma unroll
  for (int rt = 0; rt < 2; rt++) {
#pragma unroll
    for (int r = 0; r < 4; r++) {
      int row = bm + wave * 32 + rt * 16 + quad * 4 + r;
      float ps = 0.f, pd = 0.f;
#pragma unroll
      for (int ct = 0; ct < 4; ct++) {
        float v = acc[rt][ct][r];
        ps += v * asw[ct];
        pd += v * adw[ct];
        if (row < M) hb[(size_t)row * HC + bn + ct * 16 + l15] = f2bf(v);
      }
#pragma unroll
      for (int d = 1; d < 16; d <<= 1) {
        ps += __shfl_xor(ps, d);
        pd += __shfl_xor(pd, d);
      }
      if (l15 == 0 && row < M) {
        alsrc[row * NHEAD + head] = ps;
        aldst[row * NHEAD + head] = pd;
      }
    }
  }
}

// ---- fused segment softmax + aggregation -----------------------------------
// Pass A (alpha+max+denom): mapping h=t&7, edge-slot eo=t>>3, stride 32;
// alpha cached in 8 registers (deg<=256 fast path; overflow recomputes).
// Pass B (gather): one WAVE per edge, dwordx4 row loads, lane owns 8 channels;
// cross-wave channel reduction in LDS at the end.
template <bool RELU, bool FINAL>
__global__ __launch_bounds__(256) void agg_k(const u16* __restrict__ hb,
                                             const float* __restrict__ alsrc,
                                             const float* __restrict__ aldst,
                                             const int* __restrict__ rowptr,
                                             const int* __restrict__ esrc,
                                             const float* __restrict__ elw,
                                             const float* __restrict__ bias,
                                             u32* __restrict__ outB,
                                             float* __restrict__ outF,
                                             const int* __restrict__ flag) {
  const int n = blockIdx.x, t = threadIdx.x;
  const int lane = t & 63, wv = t >> 6;
  const int h = t & 7, eo = t >> 3;
  __shared__ float sred[32];
  __shared__ float sd[NHEAD];
  __shared__ float sw[32 * NHEAD];
  __shared__ int ss[32];
  __shared__ float red4[4][HC];
  const int beg = rowptr[n];
  const int deg = rowptr[n + 1] - beg;
  const float aln = aldst[n * NHEAD + h];

  // ---- pass A1: alpha into registers + per-head max ----
  float areg[8];
  int sreg[8];
  float m = -1e30f;
#pragma unroll
  for (int c = 0; c < 8; c++) {
    int j = c * 32 + eo;
    float a = -1e30f;
    int s = 0;
    if (j < deg) {
      int e = beg + j;
      s = esrc[e];
      a = alsrc[s * NHEAD + h] + aln;
      a = (a > 0.f) ? a : NEG * a;
      a += elw[e];
      m = fmaxf(m, a);
    }
    areg[c] = a;
    sreg[c] = s;
  }
  for (int j = 256 + eo; j < deg; j += 32) {  // overflow (deg>256): recompute
    int e = beg + j;
    float a = alsrc[esrc[e] * NHEAD + h] + aln;
    a = (a > 0.f) ? a : NEG * a;
    m = fmaxf(m, a + elw[e]);
  }
  m = fmaxf(m, __shfl_xor(m, 8));
  m = fmaxf(m, __shfl_xor(m, 16));
  m = fmaxf(m, __shfl_xor(m, 32));
  if (lane < 8) sred[wv * 8 + lane] = m;
  __syncthreads();
  const float mh = fmaxf(fmaxf(sred[h], sred[8 + h]), fmaxf(sred[16 + h], sred[24 + h]));
  __syncthreads();  // sred reused below
  // ---- pass A2: exp weights into registers + per-head denom ----
  float sum = 0.f;
#pragma unroll
  for (int c = 0; c < 8; c++) {
    int j = c * 32 + eo;
    if (j < deg) {
      float w = expf(areg[c] - mh);
      areg[c] = w;
      sum += w;
    }
  }
  for (int j = 256 + eo; j < deg; j += 32) {
    int e = beg + j;
    float a = alsrc[esrc[e] * NHEAD + h] + aln;
    a = (a > 0.f) ? a : NEG * a;
    sum += expf(a + elw[e] - mh);
  }
  sum += __shfl_xor(sum, 8);
  sum += __shfl_xor(sum, 16);
  sum += __shfl_xor(sum, 32);
  if (lane < 8) sred[wv * 8 + lane] = sum;
  __syncthreads();
  if (t < 8) sd[t] = sred[t] + sred[8 + t] + sred[16 + t] + sred[24 + t];
  // sd is read only after chunk-loop barriers below (deg>=1 guarantees >=1 chunk)

  // ---- pass B: gather-aggregate, one wave per edge ----
  const int hh = lane >> 3;
  const int chbase = lane * 8;
  float acc[8] = {};
#pragma unroll
  for (int c = 0; c < 8; c++) {
    const int cb = c * 32;
    if (cb < deg) {
      if (cb + eo < deg) {
        sw[eo * NHEAD + h] = areg[c];
        if (h == 0) ss[eo] = sreg[c];
      }
      __syncthreads();
      const int cnt = min(32, deg - cb);
      for (int i = wv; i < cnt; i += 4) {
        const int s = ss[i];
        const float w = sw[i * NHEAD + hh];
        const int4 p = *(const int4*)(hb + (size_t)s * HC + chbase);
        const u32 p0 = (u32)p.x, p1 = (u32)p.y, p2 = (u32)p.z, p3 = (u32)p.w;
        acc[0] += w * bflo(p0);
        acc[1] += w * bfhi(p0);
        acc[2] += w * bflo(p1);
        acc[3] += w * bfhi(p1);
        acc[4] += w * bflo(p2);
        acc[5] += w * bfhi(p2);
        acc[6] += w * bflo(p3);
        acc[7] += w * bfhi(p3);
      }
      __syncthreads();
    }
  }
  for (int cb = 256; cb < deg; cb += 32) {  // overflow chunks
    if (cb + eo < deg) {
      int e = beg + cb + eo;
      int s = esrc[e];
      float a = alsrc[s * NHEAD + h] + aln;
      a = (a > 0.f) ? a : NEG * a;
      sw[eo * NHEAD + h] = expf(a + elw[e] - mh);
      if (h == 0) ss[eo] = s;
    }
    __syncthreads();
    const int cnt = min(32, deg - cb);
    for (int i = wv; i < cnt; i += 4) {
      const int s = ss[i];
      const float w = sw[i * NHEAD + hh];
      const int4 p = *(const int4*)(hb + (size_t)s * HC + chbase);
      const u32 p0 = (u32)p.x, p1 = (u32)p.y, p2 = (u32)p.z, p3 = (u32)p.w;
      acc[0] += w * bflo(p0);
      acc[1] += w * bfhi(p0);
      acc[2] += w * bflo(p1);
      acc[3] += w * bfhi(p1);
      acc[4] += w * bflo(p2);
      acc[5] += w * bfhi(p2);
      acc[6] += w * bflo(p3);
      acc[7] += w * bfhi(p3);
    }
    __syncthreads();
  }
  // ---- cross-wave channel reduction + epilogue ----
#pragma unroll
  for (int j = 0; j < 8; j++) red4[wv][chbase + j] = acc[j];
  __syncthreads();
  const int c0 = 2 * t, c1 = 2 * t + 1;
  float v0 = red4[0][c0] + red4[1][c0] + red4[2][c0] + red4[3][c0];
  float v1 = red4[0][c1] + red4[1][c1] + red4[2][c1] + red4[3][c1];
  const float inv = 1.f / sd[t >> 5];
  v0 = v0 * inv + bias[c0];
  v1 = v1 * inv + bias[c1];
  if (RELU) {
    v0 = fmaxf(v0, 0.f);
    v1 = fmaxf(v1, 0.f);
  }
  if (FINAL && !(*flag)) {
    outF[(size_t)n * HC + c0] = v0;
    outF[(size_t)n * HC + c1] = v1;
  } else {
    outB[(size_t)n * (HC / 2) + t] = (u32)f2bf(v0) | ((u32)f2bf(v1) << 16);
  }
}

// ---------------- workspace layout -----------------------------------------
static constexpr size_t algn(size_t x) { return (x + 255) & ~(size_t)255; }
static constexpr size_t oFlag = 0;
static constexpr size_t oXB = algn(oFlag + 256);
static constexpr size_t oW1T = algn(oXB + (size_t)SX * 2);
static constexpr size_t oW2T = algn(oW1T + (size_t)SW1 * 2);
static constexpr size_t oAtt = algn(oW2T + (size_t)SW2 * 2);
static constexpr size_t oHB = algn(oAtt + (size_t)SATT * 4);     // bf16 h
static constexpr size_t oO1B = algn(oHB + (size_t)NN * HC * 2);  // bf16 o1
static constexpr size_t oAS = algn(oO1B + (size_t)NN * HC * 2);
static constexpr size_t oAD = algn(oAS + (size_t)NN * NHEAD * 4);
static constexpr size_t oRP = algn(oAD + (size_t)NN * NHEAD * 4);
static constexpr size_t oCnt = algn(oRP + (size_t)(NN + 1) * 4);
static constexpr size_t oWcur = algn(oCnt + (size_t)NN * 4);
static constexpr size_t oESrc = algn(oWcur + (size_t)NN * 4);
static constexpr size_t oELW = algn(oESrc + (size_t)ETOT * 4);

extern "C" void kernel_launch(void* const* d_in, const int* in_sizes, int n_in,
                              void* d_out, int out_size, void* d_ws, size_t ws_size,
                              hipStream_t stream) {
  (void)in_sizes; (void)n_in; (void)out_size; (void)ws_size;
  const int* ei = (const int*)d_in[1];

  char* ws = (char*)d_ws;
  int* flag = (int*)(ws + oFlag);
  u16* xb = (u16*)(ws + oXB);
  u16* w1t = (u16*)(ws + oW1T);
  u16* w2t = (u16*)(ws + oW2T);
  float* attf = (float*)(ws + oAtt);
  float* as1f = attf, *ad1f = attf + 512, *b1f = attf + 1024;
  float* as2f = attf + 1536, *ad2f = attf + 2048, *b2f = attf + 2560;
  u16* hb = (u16*)(ws + oHB);
  u16* o1b = (u16*)(ws + oO1B);
  float* alsrc = (float*)(ws + oAS);
  float* aldst = (float*)(ws + oAD);
  int* rowptr = (int*)(ws + oRP);
  int* counts = (int*)(ws + oCnt);
  int* wcur = (int*)(ws + oWcur);
  int* esrc = (int*)(ws + oESrc);
  float* elw = (float*)(ws + oELW);

  const int eb = (ETOT + 255) / 256;
  const int cvb = (SX + SATT + 255) / 256;  // covers ETOT too (SX > ETOT)

  zdetect_k<<<(NN + 255) / 256, 256, 0, stream>>>((const u16*)d_in[0], flag, counts);
  cvt_count_k<<<cvb, 256, 0, stream>>>(d_in[0], d_in[4], d_in[5], d_in[6],
                                       d_in[8], d_in[9], d_in[10], ei,
                                       xb, attf, counts, flag);
  wtrans_k<<<96, 256, 0, stream>>>(d_in[3], d_in[7], w1t, w2t, flag);
  scan_k<<<1, 1024, 0, stream>>>(counts, rowptr, wcur);
  fill_k<<<eb, 256, 0, stream>>>(ei, d_in[2], flag, wcur, esrc, elw);

  // ---- layer 1 ----
  gemm_mfma<<<dim3(8, (NN + BM - 1) / BM), 256, 0, stream>>>(
      xb, w1t, as1f, ad1f, hb, alsrc, aldst, NN, CIN);
  agg_k<true, false><<<NN, 256, 0, stream>>>(hb, alsrc, aldst, rowptr, esrc, elw,
                                             b1f, (u32*)o1b, nullptr, flag);

  // ---- layer 2 ----
  gemm_mfma<<<dim3(8, (NN + BM - 1) / BM), 256, 0, stream>>>(
      o1b, w2t, as2f, ad2f, hb, alsrc, aldst, NN, HC);
  agg_k<false, true><<<NN, 256, 0, stream>>>(hb, alsrc, aldst, rowptr, esrc, elw,
                                             b2f, (u32*)d_out, (float*)d_out, flag);
}

// Round 8
// 266.983 us; speedup vs baseline: 4.3886x; 1.0157x over previous
//
#include <hip/hip_runtime.h>
#include <hip/hip_bf16.h>

#define NN 10000
#define EE 320000
#define ETOT (EE + NN)
#define CIN 256
#define HC 512
#define NHEAD 8
#define NEG 0.2f

#define SX (NN * CIN)
#define SATT (6 * 512)

using bf16x8 = __attribute__((ext_vector_type(8))) short;
using f32x4 = __attribute__((ext_vector_type(4))) float;
typedef unsigned short u16;
typedef unsigned int u32;

__device__ __forceinline__ u16 f2bf(float f) {
  __hip_bfloat16 b = __float2bfloat16(f);
  return *(u16*)&b;
}
__device__ __forceinline__ float bflo(u32 p) { return __uint_as_float(p << 16); }
__device__ __forceinline__ float bfhi(u32 p) { return __uint_as_float(p & 0xFFFF0000u); }

// ============ prep: detect + convert + degree-count + W transpose ==========
#define PB_X ((SX + 255) / 256)
#define PB_ATT ((SATT + 255) / 256)
#define PB_CNT ((ETOT + 255) / 256)
#define PB_WT 96
#define PB_TOT (PB_X + PB_ATT + PB_CNT + PB_WT)

__global__ __launch_bounds__(256) void prep_k(
    const void* __restrict__ x, const void* __restrict__ w1,
    const void* __restrict__ w2,
    const void* a0, const void* a1, const void* a2,
    const void* a3, const void* a4, const void* a5,
    const int* __restrict__ ei,
    u16* __restrict__ xb, u16* __restrict__ w1t, u16* __restrict__ w2t,
    float* __restrict__ attf, int* __restrict__ counts, int* __restrict__ flag) {
  const int b = blockIdx.x, t = threadIdx.x;
  __shared__ int sbad;
  if (t == 0) sbad = 0;
  __syncthreads();
  {
    const u16* xu = (const u16*)x;
    unsigned e0 = (xu[2 * t] >> 7) & 0xFFu;
    unsigned e1 = (xu[2 * t + 1] >> 7) & 0xFFu;
    if (e0 >= 0xC8u || e1 >= 0xC8u) sbad = 1;
  }
  __syncthreads();
  const bool bf = (sbad == 0);
  if (b == 0 && t == 0) *flag = bf ? 1 : 0;

  if (b < PB_X) {
    int i = b * 256 + t;
    if (i < SX) xb[i] = bf ? ((const u16*)x)[i] : f2bf(((const float*)x)[i]);
  } else if (b < PB_X + PB_ATT) {
    int j = (b - PB_X) * 256 + t;
    if (j < SATT) {
      const void* ps[6] = {a0, a1, a2, a3, a4, a5};
      const void* p = ps[j >> 9];
      int k = j & 511;
      attf[j] = bf ? __bfloat162float(((const __hip_bfloat16*)p)[k])
                   : ((const float*)p)[k];
    }
  } else if (b < PB_X + PB_ATT + PB_CNT) {
    int e = (b - PB_X - PB_ATT) * 256 + t;
    if (e < ETOT) {
      int d = (e < EE) ? ei[EE + e] : (e - EE);
      atomicAdd(&counts[d], 1);
    }
  } else {
    __shared__ u16 tile[64][72];
    int wb = b - (PB_X + PB_ATT + PB_CNT);
    const void* src;
    u16* dst;
    int K, tk, tn;
    if (wb < 32) { src = w1; dst = w1t; K = CIN; tk = (wb >> 3) * 64; tn = (wb & 7) * 64; }
    else { wb -= 32; src = w2; dst = w2t; K = HC; tk = (wb >> 3) * 64; tn = (wb & 7) * 64; }
    const int r = t >> 2, cb = (t & 3) * 16;
    if (bf) {
      const u16* s = (const u16*)src + (size_t)(tk + r) * HC + tn + cb;
      *(int4*)&tile[r][cb] = ((const int4*)s)[0];
      *(int4*)&tile[r][cb + 8] = ((const int4*)s)[1];
    } else {
      const float* s = (const float*)src + (size_t)(tk + r) * HC + tn + cb;
#pragma unroll
      for (int j = 0; j < 16; j++) tile[r][cb + j] = f2bf(s[j]);
    }
    __syncthreads();
    union { u16 o[16]; int4 v[2]; } u;
#pragma unroll
    for (int j = 0; j < 16; j++) u.o[j] = tile[cb + j][r];
    int4* dp = (int4*)(dst + (size_t)(tn + r) * K + tk + cb);
    dp[0] = u.v[0];
    dp[1] = u.v[1];
  }
}

// ============ exclusive scan: rowptr + working cursors ======================
__global__ __launch_bounds__(1024) void scan_k(const int* __restrict__ counts,
                                               int* __restrict__ rowptr,
                                               int* __restrict__ wcur) {
  __shared__ int buf[1024];
  const int t = threadIdx.x;
  int loc[10];
  int s = 0;
#pragma unroll
  for (int j = 0; j < 10; j++) {
    int i = t * 10 + j;
    s += (i < NN) ? counts[i] : 0;
    loc[j] = s;
  }
  buf[t] = s;
  __syncthreads();
  for (int off = 1; off < 1024; off <<= 1) {
    int v = (t >= off) ? buf[t - off] : 0;
    __syncthreads();
    buf[t] += v;
    __syncthreads();
  }
  int base = (t > 0) ? buf[t - 1] : 0;
  int prev = 0;
#pragma unroll
  for (int j = 0; j < 10; j++) {
    int i = t * 10 + j;
    if (i < NN) {
      rowptr[i + 1] = base + loc[j];
      wcur[i] = base + prev;
    }
    prev = loc[j];
  }
  if (t == 0) rowptr[0] = 0;
}

// ============ CSR fill ======================================================
__global__ void fill_k(const int* __restrict__ ei, const void* __restrict__ ew,
                       const int* __restrict__ flag, int* __restrict__ wcur,
                       int* __restrict__ esrc, float* __restrict__ elw) {
  int e = blockIdx.x * blockDim.x + threadIdx.x;
  if (e >= ETOT) return;
  int s, d;
  float lw;
  if (e < EE) {
    s = ei[e];
    d = ei[EE + e];
    float w = (*flag) ? __bfloat162float(((const __hip_bfloat16*)ew)[e])
                      : ((const float*)ew)[e];
    lw = log2f(w);
  } else {
    s = d = e - EE;
    lw = 0.f;
  }
  int pos = atomicAdd(&wcur[d], 1);
  esrc[pos] = s;
  elw[pos] = lw;
}

// ============ MFMA GEMM + fused logits ======================================
#define BM 64
#define BN 128
#define BK 64
#define LSTR 72

__global__ __launch_bounds__(256) void gemm_mfma(const u16* __restrict__ A,
                                                 const u16* __restrict__ Wt,
                                                 const float* __restrict__ as_w,
                                                 const float* __restrict__ ad_w,
                                                 u16* __restrict__ hb,
                                                 float* __restrict__ alsrc,
                                                 float* __restrict__ aldst,
                                                 int M, int K) {
  __shared__ u16 As[BM * LSTR];
  __shared__ u16 Bs[BN * LSTR];
  __shared__ float sps[2][2][BM], spd[2][2][BM];
  const int bx = blockIdx.x;
  const int bm = blockIdx.y * BM, bn = bx * BN;
  const int t = threadIdx.x, wv = t >> 6, lane = t & 63;
  const int l15 = lane & 15, quad = lane >> 4;
  f32x4 acc[4][2] = {};
  for (int k0 = 0; k0 < K; k0 += BK) {
    {
      int row = t >> 2, kq = (t & 3) * 16;
      int gr = bm + row;
      int4 v0 = make_int4(0, 0, 0, 0), v1 = v0;
      if (gr < M) {
        const int4* gp = (const int4*)(A + (size_t)gr * K + k0 + kq);
        v0 = gp[0];
        v1 = gp[1];
      }
      int4* lp = (int4*)(As + row * LSTR + kq);
      lp[0] = v0;
      lp[1] = v1;
    }
    {
      int row = t >> 1, kq = (t & 1) * 32;
      const int4* gp = (const int4*)(Wt + (size_t)(bn + row) * K + k0 + kq);
      int4* lp = (int4*)(Bs + row * LSTR + kq);
      lp[0] = gp[0];
      lp[1] = gp[1];
      lp[2] = gp[2];
      lp[3] = gp[3];
    }
    __syncthreads();
#pragma unroll
    for (int kk = 0; kk < 2; kk++) {
      bf16x8 bfr[2];
#pragma unroll
      for (int ct = 0; ct < 2; ct++)
        bfr[ct] = *(const bf16x8*)(Bs + (wv * 32 + ct * 16 + l15) * LSTR + kk * 32 + quad * 8);
#pragma unroll
      for (int rt = 0; rt < 4; rt++) {
        bf16x8 af = *(const bf16x8*)(As + (rt * 16 + l15) * LSTR + kk * 32 + quad * 8);
#pragma unroll
        for (int ct = 0; ct < 2; ct++)
          acc[rt][ct] = __builtin_amdgcn_mfma_f32_16x16x32_bf16(af, bfr[ct],
                                                                acc[rt][ct], 0, 0, 0);
      }
    }
    __syncthreads();
  }
  const int head = bx * 2 + (wv >> 1);
  float asw[2], adw[2];
#pragma unroll
  for (int ct = 0; ct < 2; ct++) {
    int c = head * 64 + (wv & 1) * 32 + ct * 16 + l15;
    asw[ct] = as_w[c];
    adw[ct] = ad_w[c];
  }
#pragma unroll
  for (int rt = 0; rt < 4; rt++) {
#pragma unroll
    for (int r = 0; r < 4; r++) {
      int rib = rt * 16 + quad * 4 + r;
      int row = bm + rib;
      float ps = 0.f, pd = 0.f;
#pragma unroll
      for (int ct = 0; ct < 2; ct++) {
        float v = acc[rt][ct][r];
        ps += v * asw[ct];
        pd += v * adw[ct];
        if (row < M)
          hb[(size_t)row * HC + bn + wv * 32 + ct * 16 + l15] = f2bf(v);
      }
#pragma unroll
      for (int d = 1; d < 16; d <<= 1) {
        ps += __shfl_xor(ps, d);
        pd += __shfl_xor(pd, d);
      }
      if (l15 == 0) {
        sps[wv >> 1][wv & 1][rib] = ps;
        spd[wv >> 1][wv & 1][rib] = pd;
      }
    }
  }
  __syncthreads();
  if (t < 2 * BM) {
    int rib = t & 63, hs = t >> 6;
    int row = bm + rib;
    if (row < M) {
      alsrc[row * NHEAD + bx * 2 + hs] = sps[hs][0][rib] + sps[hs][1][rib];
      aldst[row * NHEAD + bx * 2 + hs] = spd[hs][0][rib] + spd[hs][1][rib];
    }
  }
}

// ============ fused segment softmax + aggregation ===========================
// FIX vs round 7: red4 swizzle removed — it collided at 16-lane boundaries
// (lane 15 off=3 wrote idx 123..130, lane 16 off=0 wrote 128..135 -> race).
// Plain red4[4][512] is collision-free; its bank conflicts measured ~64
// cycles/block in round 6 (noise).
template <bool RELU, bool FINAL>
__global__ __launch_bounds__(256) void agg_k(const u16* __restrict__ hb,
                                             const float* __restrict__ alsrc,
                                             const float* __restrict__ aldst,
                                             const int* __restrict__ rowptr,
                                             const int* __restrict__ esrc,
                                             const float* __restrict__ elw,
                                             const float* __restrict__ bias,
                                             u32* __restrict__ outB,
                                             float* __restrict__ outF,
                                             const int* __restrict__ flag) {
  const int n = blockIdx.x, t = threadIdx.x;
  const int lane = t & 63, wv = t >> 6;
  const int h = t & 7, eo = t >> 3;
  const int hh = lane >> 3;
  __shared__ float sw[8 * 260];
  __shared__ int ss[256];
  __shared__ float sred[32];
  __shared__ float smh[8], sd[8];
  __shared__ float red4[4][HC];
  const int beg = rowptr[n];
  const int deg = rowptr[n + 1] - beg;
  const float4 dd0 = *(const float4*)(aldst + (size_t)n * NHEAD);
  const float4 dd1 = *(const float4*)(aldst + (size_t)n * NHEAD + 4);
  const int chbase = lane * 8;
  float acc[8] = {};

  if (deg <= 256) {
    if (t < deg) {
      int e = beg + t;
      int s = esrc[e];
      float lw = elw[e];
      float4 q0 = *(const float4*)(alsrc + (size_t)s * NHEAD);
      float4 q1 = *(const float4*)(alsrc + (size_t)s * NHEAD + 4);
      float a;
      a = q0.x + dd0.x; a = (a > 0.f) ? a : NEG * a; sw[0 * 260 + t] = a + lw;
      a = q0.y + dd0.y; a = (a > 0.f) ? a : NEG * a; sw[1 * 260 + t] = a + lw;
      a = q0.z + dd0.z; a = (a > 0.f) ? a : NEG * a; sw[2 * 260 + t] = a + lw;
      a = q0.w + dd0.w; a = (a > 0.f) ? a : NEG * a; sw[3 * 260 + t] = a + lw;
      a = q1.x + dd1.x; a = (a > 0.f) ? a : NEG * a; sw[4 * 260 + t] = a + lw;
      a = q1.y + dd1.y; a = (a > 0.f) ? a : NEG * a; sw[5 * 260 + t] = a + lw;
      a = q1.z + dd1.z; a = (a > 0.f) ? a : NEG * a; sw[6 * 260 + t] = a + lw;
      a = q1.w + dd1.w; a = (a > 0.f) ? a : NEG * a; sw[7 * 260 + t] = a + lw;
      ss[t] = s;
    }
    __syncthreads();
    float m = -1e30f;
#pragma unroll
    for (int c = 0; c < 8; c++) {
      int j = c * 32 + eo;
      if (j < deg) m = fmaxf(m, sw[h * 260 + j]);
    }
    m = fmaxf(m, __shfl_xor(m, 8));
    m = fmaxf(m, __shfl_xor(m, 16));
    m = fmaxf(m, __shfl_xor(m, 32));
    if (lane < 8) sred[wv * 8 + lane] = m;
    __syncthreads();
    const float mh = fmaxf(fmaxf(sred[h], sred[8 + h]), fmaxf(sred[16 + h], sred[24 + h]));
    __syncthreads();
    float sum = 0.f;
#pragma unroll
    for (int c = 0; c < 8; c++) {
      int j = c * 32 + eo;
      if (j < deg) {
        float w = expf(sw[h * 260 + j] - mh);
        sw[h * 260 + j] = w;
        sum += w;
      }
    }
    sum += __shfl_xor(sum, 8);
    sum += __shfl_xor(sum, 16);
    sum += __shfl_xor(sum, 32);
    if (lane < 8) sred[wv * 8 + lane] = sum;
    __syncthreads();
    if (t < 8) sd[t] = sred[t] + sred[8 + t] + sred[16 + t] + sred[24 + t];
    for (int i = wv; i < deg; i += 4) {
      const int s = ss[i];
      const float w = sw[hh * 260 + i];
      const int4 p = *(const int4*)(hb + (size_t)s * HC + chbase);
      const u32 p0 = (u32)p.x, p1 = (u32)p.y, p2 = (u32)p.z, p3 = (u32)p.w;
      acc[0] += w * bflo(p0);
      acc[1] += w * bfhi(p0);
      acc[2] += w * bflo(p1);
      acc[3] += w * bfhi(p1);
      acc[4] += w * bflo(p2);
      acc[5] += w * bfhi(p2);
      acc[6] += w * bflo(p3);
      acc[7] += w * bfhi(p3);
    }
  } else {
    const float aln = aldst[(size_t)n * NHEAD + h];
    float m = -1e30f;
    for (int j = eo; j < deg; j += 32) {
      int e = beg + j;
      float a = alsrc[(size_t)esrc[e] * NHEAD + h] + aln;
      a = (a > 0.f) ? a : NEG * a;
      m = fmaxf(m, a + elw[e]);
    }
    m = fmaxf(m, __shfl_xor(m, 8));
    m = fmaxf(m, __shfl_xor(m, 16));
    m = fmaxf(m, __shfl_xor(m, 32));
    if (lane < 8) sred[wv * 8 + lane] = m;
    __syncthreads();
    const float mh = fmaxf(fmaxf(sred[h], sred[8 + h]), fmaxf(sred[16 + h], sred[24 + h]));
    if (t < 8) smh[t] = mh;
    __syncthreads();
    float sum = 0.f;
    for (int j = eo; j < deg; j += 32) {
      int e = beg + j;
      float a = alsrc[(size_t)esrc[e] * NHEAD + h] + aln;
      a = (a > 0.f) ? a : NEG * a;
      sum += expf(a + elw[e] - mh);
    }
    sum += __shfl_xor(sum, 8);
    sum += __shfl_xor(sum, 16);
    sum += __shfl_xor(sum, 32);
    if (lane < 8) sred[wv * 8 + lane] = sum;
    __syncthreads();
    if (t < 8) sd[t] = sred[t] + sred[8 + t] + sred[16 + t] + sred[24 + t];
    for (int cb = 0; cb < deg; cb += 256) {
      int j = cb + t;
      if (j < deg) {
        int e = beg + j;
        int s = esrc[e];
        float lw = elw[e];
        float4 q0 = *(const float4*)(alsrc + (size_t)s * NHEAD);
        float4 q1 = *(const float4*)(alsrc + (size_t)s * NHEAD + 4);
        float a;
        a = q0.x + dd0.x; a = (a > 0.f) ? a : NEG * a; sw[0 * 260 + t] = expf(a + lw - smh[0]);
        a = q0.y + dd0.y; a = (a > 0.f) ? a : NEG * a; sw[1 * 260 + t] = expf(a + lw - smh[1]);
        a = q0.z + dd0.z; a = (a > 0.f) ? a : NEG * a; sw[2 * 260 + t] = expf(a + lw - smh[2]);
        a = q0.w + dd0.w; a = (a > 0.f) ? a : NEG * a; sw[3 * 260 + t] = expf(a + lw - smh[3]);
        a = q1.x + dd1.x; a = (a > 0.f) ? a : NEG * a; sw[4 * 260 + t] = expf(a + lw - smh[4]);
        a = q1.y + dd1.y; a = (a > 0.f) ? a : NEG * a; sw[5 * 260 + t] = expf(a + lw - smh[5]);
        a = q1.z + dd1.z; a = (a > 0.f) ? a : NEG * a; sw[6 * 260 + t] = expf(a + lw - smh[6]);
        a = q1.w + dd1.w; a = (a > 0.f) ? a : NEG * a; sw[7 * 260 + t] = expf(a + lw - smh[7]);
        ss[t] = s;
      }
      __syncthreads();
      int cnt = min(256, deg - cb);
      for (int i = wv; i < cnt; i += 4) {
        const int s = ss[i];
        const float w = sw[hh * 260 + i];
        const int4 p = *(const int4*)(hb + (size_t)s * HC + chbase);
        const u32 p0 = (u32)p.x, p1 = (u32)p.y, p2 = (u32)p.z, p3 = (u32)p.w;
        acc[0] += w * bflo(p0);
        acc[1] += w * bfhi(p0);
        acc[2] += w * bflo(p1);
        acc[3] += w * bfhi(p1);
        acc[4] += w * bflo(p2);
        acc[5] += w * bfhi(p2);
        acc[6] += w * bflo(p3);
        acc[7] += w * bfhi(p3);
      }
      __syncthreads();
    }
  }
  // ---- cross-wave channel reduction (plain, collision-free) + epilogue ----
#pragma unroll
  for (int j = 0; j < 8; j++) red4[wv][chbase + j] = acc[j];
  __syncthreads();
  const int c0 = 2 * t;
  float v0 = red4[0][c0] + red4[1][c0] + red4[2][c0] + red4[3][c0];
  float v1 = red4[0][c0 + 1] + red4[1][c0 + 1] + red4[2][c0 + 1] + red4[3][c0 + 1];
  const float inv = 1.f / sd[t >> 5];
  v0 = v0 * inv + bias[c0];
  v1 = v1 * inv + bias[c0 + 1];
  if (RELU) {
    v0 = fmaxf(v0, 0.f);
    v1 = fmaxf(v1, 0.f);
  }
  if (FINAL && !(*flag)) {
    outF[(size_t)n * HC + c0] = v0;
    outF[(size_t)n * HC + c0 + 1] = v1;
  } else {
    outB[(size_t)n * (HC / 2) + t] = (u32)f2bf(v0) | ((u32)f2bf(v1) << 16);
  }
}

// ---------------- workspace layout -----------------------------------------
static constexpr size_t algn(size_t x) { return (x + 255) & ~(size_t)255; }
static constexpr size_t oFlag = 0;
static constexpr size_t oXB = algn(oFlag + 256);
static constexpr size_t oW1T = algn(oXB + (size_t)SX * 2);
static constexpr size_t oW2T = algn(oW1T + (size_t)CIN * HC * 2);
static constexpr size_t oAtt = algn(oW2T + (size_t)HC * HC * 2);
static constexpr size_t oHB = algn(oAtt + (size_t)SATT * 4);
static constexpr size_t oO1B = algn(oHB + (size_t)NN * HC * 2);
static constexpr size_t oAS = algn(oO1B + (size_t)NN * HC * 2);
static constexpr size_t oAD = algn(oAS + (size_t)NN * NHEAD * 4);
static constexpr size_t oRP = algn(oAD + (size_t)NN * NHEAD * 4);
static constexpr size_t oCnt = algn(oRP + (size_t)(NN + 1) * 4);
static constexpr size_t oWcur = algn(oCnt + (size_t)NN * 4);
static constexpr size_t oESrc = algn(oWcur + (size_t)NN * 4);
static constexpr size_t oELW = algn(oESrc + (size_t)ETOT * 4);

extern "C" void kernel_launch(void* const* d_in, const int* in_sizes, int n_in,
                              void* d_out, int out_size, void* d_ws, size_t ws_size,
                              hipStream_t stream) {
  (void)in_sizes; (void)n_in; (void)out_size; (void)ws_size;
  const int* ei = (const int*)d_in[1];

  char* ws = (char*)d_ws;
  int* flag = (int*)(ws + oFlag);
  u16* xb = (u16*)(ws + oXB);
  u16* w1t = (u16*)(ws + oW1T);
  u16* w2t = (u16*)(ws + oW2T);
  float* attf = (float*)(ws + oAtt);
  float* as1f = attf, *ad1f = attf + 512, *b1f = attf + 1024;
  float* as2f = attf + 1536, *ad2f = attf + 2048, *b2f = attf + 2560;
  u16* hb = (u16*)(ws + oHB);
  u16* o1b = (u16*)(ws + oO1B);
  float* alsrc = (float*)(ws + oAS);
  float* aldst = (float*)(ws + oAD);
  int* rowptr = (int*)(ws + oRP);
  int* counts = (int*)(ws + oCnt);
  int* wcur = (int*)(ws + oWcur);
  int* esrc = (int*)(ws + oESrc);
  float* elw = (float*)(ws + oELW);

  hipMemsetAsync(counts, 0, (size_t)NN * 4, stream);
  prep_k<<<PB_TOT, 256, 0, stream>>>(d_in[0], d_in[3], d_in[7],
                                     d_in[4], d_in[5], d_in[6],
                                     d_in[8], d_in[9], d_in[10], ei,
                                     xb, w1t, w2t, attf, counts, flag);
  scan_k<<<1, 1024, 0, stream>>>(counts, rowptr, wcur);
  fill_k<<<(ETOT + 255) / 256, 256, 0, stream>>>(ei, d_in[2], flag, wcur, esrc, elw);

  // ---- layer 1 ----
  gemm_mfma<<<dim3(HC / BN, (NN + BM - 1) / BM), 256, 0, stream>>>(
      xb, w1t, as1f, ad1f, hb, alsrc, aldst, NN, CIN);
  agg_k<true, false><<<NN, 256, 0, stream>>>(hb, alsrc, aldst, rowptr, esrc, elw,
                                             b1f, (u32*)o1b, nullptr, flag);

  // ---- layer 2 ----
  gemm_mfma<<<dim3(HC / BN, (NN + BM - 1) / BM), 256, 0, stream>>>(
      o1b, w2t, as2f, ad2f, hb, alsrc, aldst, NN, HC);
  agg_k<false, true><<<NN, 256, 0, stream>>>(hb, alsrc, aldst, rowptr, esrc, elw,
                                             b2f, (u32*)d_out, (float*)d_out, flag);
}

// Round 9
// 263.882 us; speedup vs baseline: 4.4402x; 1.0118x over previous
//
#include <hip/hip_runtime.h>
#include <hip/hip_bf16.h>

#define NN 10000
#define EE 320000
#define ETOT (EE + NN)
#define CIN 256
#define HC 512
#define NHEAD 8
#define NEG 0.2f

#define SX (NN * CIN)
#define SATT (6 * 512)

using bf16x8 = __attribute__((ext_vector_type(8))) short;
using f32x4 = __attribute__((ext_vector_type(4))) float;
typedef unsigned short u16;
typedef unsigned int u32;

__device__ __forceinline__ u16 f2bf(float f) {
  __hip_bfloat16 b = __float2bfloat16(f);
  return *(u16*)&b;
}
__device__ __forceinline__ float bflo(u32 p) { return __uint_as_float(p << 16); }
__device__ __forceinline__ float bfhi(u32 p) { return __uint_as_float(p & 0xFFFF0000u); }

// ============ prep: detect + convert + degree-count + W transpose ==========
#define PB_X ((SX + 255) / 256)
#define PB_ATT ((SATT + 255) / 256)
#define PB_CNT ((ETOT + 255) / 256)
#define PB_WT 96
#define PB_TOT (PB_X + PB_ATT + PB_CNT + PB_WT)

__global__ __launch_bounds__(256) void prep_k(
    const void* __restrict__ x, const void* __restrict__ w1,
    const void* __restrict__ w2,
    const void* a0, const void* a1, const void* a2,
    const void* a3, const void* a4, const void* a5,
    const int* __restrict__ ei,
    u16* __restrict__ xb, u16* __restrict__ w1t, u16* __restrict__ w2t,
    float* __restrict__ attf, int* __restrict__ counts, int* __restrict__ flag) {
  const int b = blockIdx.x, t = threadIdx.x;
  __shared__ int sbad;
  if (t == 0) sbad = 0;
  __syncthreads();
  {
    const u16* xu = (const u16*)x;
    unsigned e0 = (xu[2 * t] >> 7) & 0xFFu;
    unsigned e1 = (xu[2 * t + 1] >> 7) & 0xFFu;
    if (e0 >= 0xC8u || e1 >= 0xC8u) sbad = 1;
  }
  __syncthreads();
  const bool bf = (sbad == 0);
  if (b == 0 && t == 0) *flag = bf ? 1 : 0;

  if (b < PB_X) {
    // only needed when input is fp32 (bf16 path: gemm reads x directly)
    if (!bf) {
      int i = b * 256 + t;
      if (i < SX) xb[i] = f2bf(((const float*)x)[i]);
    }
  } else if (b < PB_X + PB_ATT) {
    int j = (b - PB_X) * 256 + t;
    if (j < SATT) {
      const void* ps[6] = {a0, a1, a2, a3, a4, a5};
      const void* p = ps[j >> 9];
      int k = j & 511;
      attf[j] = bf ? __bfloat162float(((const __hip_bfloat16*)p)[k])
                   : ((const float*)p)[k];
    }
  } else if (b < PB_X + PB_ATT + PB_CNT) {
    int e = (b - PB_X - PB_ATT) * 256 + t;
    if (e < ETOT) {
      int d = (e < EE) ? ei[EE + e] : (e - EE);
      atomicAdd(&counts[d], 1);
    }
  } else {
    __shared__ u16 tile[64][72];
    int wb = b - (PB_X + PB_ATT + PB_CNT);
    const void* src;
    u16* dst;
    int K, tk, tn;
    if (wb < 32) { src = w1; dst = w1t; K = CIN; tk = (wb >> 3) * 64; tn = (wb & 7) * 64; }
    else { wb -= 32; src = w2; dst = w2t; K = HC; tk = (wb >> 3) * 64; tn = (wb & 7) * 64; }
    const int r = t >> 2, cb = (t & 3) * 16;
    if (bf) {
      const u16* s = (const u16*)src + (size_t)(tk + r) * HC + tn + cb;
      *(int4*)&tile[r][cb] = ((const int4*)s)[0];
      *(int4*)&tile[r][cb + 8] = ((const int4*)s)[1];
    } else {
      const float* s = (const float*)src + (size_t)(tk + r) * HC + tn + cb;
#pragma unroll
      for (int j = 0; j < 16; j++) tile[r][cb + j] = f2bf(s[j]);
    }
    __syncthreads();
    union { u16 o[16]; int4 v[2]; } u;
#pragma unroll
    for (int j = 0; j < 16; j++) u.o[j] = tile[cb + j][r];
    int4* dp = (int4*)(dst + (size_t)(tn + r) * K + tk + cb);
    dp[0] = u.v[0];
    dp[1] = u.v[1];
  }
}

// ============ exclusive scan: rowptr + working cursors ======================
__global__ __launch_bounds__(1024) void scan_k(const int* __restrict__ counts,
                                               int* __restrict__ rowptr,
                                               int* __restrict__ wcur) {
  __shared__ int buf[1024];
  const int t = threadIdx.x;
  int loc[10];
  int s = 0;
#pragma unroll
  for (int j = 0; j < 10; j++) {
    int i = t * 10 + j;
    s += (i < NN) ? counts[i] : 0;
    loc[j] = s;
  }
  buf[t] = s;
  __syncthreads();
  for (int off = 1; off < 1024; off <<= 1) {
    int v = (t >= off) ? buf[t - off] : 0;
    __syncthreads();
    buf[t] += v;
    __syncthreads();
  }
  int base = (t > 0) ? buf[t - 1] : 0;
  int prev = 0;
#pragma unroll
  for (int j = 0; j < 10; j++) {
    int i = t * 10 + j;
    if (i < NN) {
      rowptr[i + 1] = base + loc[j];
      wcur[i] = base + prev;
    }
    prev = loc[j];
  }
  if (t == 0) rowptr[0] = 0;
}

// ============ CSR fill ======================================================
__global__ void fill_k(const int* __restrict__ ei, const void* __restrict__ ew,
                       const int* __restrict__ flag, int* __restrict__ wcur,
                       int* __restrict__ esrc, float* __restrict__ elw) {
  int e = blockIdx.x * blockDim.x + threadIdx.x;
  if (e >= ETOT) return;
  int s, d;
  float lw;
  if (e < EE) {
    s = ei[e];
    d = ei[EE + e];
    float w = (*flag) ? __bfloat162float(((const __hip_bfloat16*)ew)[e])
                      : ((const float*)ew)[e];
    lw = log2f(w);
  } else {
    s = d = e - EE;
    lw = 0.f;
  }
  int pos = atomicAdd(&wcur[d], 1);
  esrc[pos] = s;
  elw[pos] = lw;
}

// ============ MFMA GEMM + fused logits ======================================
#define BM 64
#define BN 128
#define BK 64
#define LSTR 72

__global__ __launch_bounds__(256) void gemm_mfma(const u16* __restrict__ A,
                                                 const void* __restrict__ Axalt,
                                                 const int* __restrict__ flagp,
                                                 const u16* __restrict__ Wt,
                                                 const float* __restrict__ as_w,
                                                 const float* __restrict__ ad_w,
                                                 u16* __restrict__ hb,
                                                 float* __restrict__ alsrc,
                                                 float* __restrict__ aldst,
                                                 int M, int K) {
  __shared__ u16 As[BM * LSTR];
  __shared__ u16 Bs[BN * LSTR];
  __shared__ float sps[2][2][BM], spd[2][2][BM];
  // bf16 fast path: read x directly from the input buffer
  const u16* Asel = (flagp && *flagp) ? (const u16*)Axalt : A;
  const int bx = blockIdx.x;
  const int bm = blockIdx.y * BM, bn = bx * BN;
  const int t = threadIdx.x, wv = t >> 6, lane = t & 63;
  const int l15 = lane & 15, quad = lane >> 4;
  f32x4 acc[4][2] = {};
  for (int k0 = 0; k0 < K; k0 += BK) {
    {
      int row = t >> 2, kq = (t & 3) * 16;
      int gr = bm + row;
      int4 v0 = make_int4(0, 0, 0, 0), v1 = v0;
      if (gr < M) {
        const int4* gp = (const int4*)(Asel + (size_t)gr * K + k0 + kq);
        v0 = gp[0];
        v1 = gp[1];
      }
      int4* lp = (int4*)(As + row * LSTR + kq);
      lp[0] = v0;
      lp[1] = v1;
    }
    {
      int row = t >> 1, kq = (t & 1) * 32;
      const int4* gp = (const int4*)(Wt + (size_t)(bn + row) * K + k0 + kq);
      int4* lp = (int4*)(Bs + row * LSTR + kq);
      lp[0] = gp[0];
      lp[1] = gp[1];
      lp[2] = gp[2];
      lp[3] = gp[3];
    }
    __syncthreads();
#pragma unroll
    for (int kk = 0; kk < 2; kk++) {
      bf16x8 bfr[2];
#pragma unroll
      for (int ct = 0; ct < 2; ct++)
        bfr[ct] = *(const bf16x8*)(Bs + (wv * 32 + ct * 16 + l15) * LSTR + kk * 32 + quad * 8);
#pragma unroll
      for (int rt = 0; rt < 4; rt++) {
        bf16x8 af = *(const bf16x8*)(As + (rt * 16 + l15) * LSTR + kk * 32 + quad * 8);
#pragma unroll
        for (int ct = 0; ct < 2; ct++)
          acc[rt][ct] = __builtin_amdgcn_mfma_f32_16x16x32_bf16(af, bfr[ct],
                                                                acc[rt][ct], 0, 0, 0);
      }
    }
    __syncthreads();
  }
  const int head = bx * 2 + (wv >> 1);
  float asw[2], adw[2];
#pragma unroll
  for (int ct = 0; ct < 2; ct++) {
    int c = head * 64 + (wv & 1) * 32 + ct * 16 + l15;
    asw[ct] = as_w[c];
    adw[ct] = ad_w[c];
  }
#pragma unroll
  for (int rt = 0; rt < 4; rt++) {
#pragma unroll
    for (int r = 0; r < 4; r++) {
      int rib = rt * 16 + quad * 4 + r;
      int row = bm + rib;
      float ps = 0.f, pd = 0.f;
#pragma unroll
      for (int ct = 0; ct < 2; ct++) {
        float v = acc[rt][ct][r];
        ps += v * asw[ct];
        pd += v * adw[ct];
        if (row < M)
          hb[(size_t)row * HC + bn + wv * 32 + ct * 16 + l15] = f2bf(v);
      }
#pragma unroll
      for (int d = 1; d < 16; d <<= 1) {
        ps += __shfl_xor(ps, d);
        pd += __shfl_xor(pd, d);
      }
      if (l15 == 0) {
        sps[wv >> 1][wv & 1][rib] = ps;
        spd[wv >> 1][wv & 1][rib] = pd;
      }
    }
  }
  __syncthreads();
  if (t < 2 * BM) {
    int rib = t & 63, hs = t >> 6;
    int row = bm + rib;
    if (row < M) {
      alsrc[row * NHEAD + bx * 2 + hs] = sps[hs][0][rib] + sps[hs][1][rib];
      aldst[row * NHEAD + bx * 2 + hs] = spd[hs][0][rib] + spd[hs][1][rib];
    }
  }
}

// ============ fused segment softmax + aggregation ===========================
// Pass B is x4-unrolled: 4 independent int4 row-gathers in flight per wave
// (agg is gather-latency-bound: r8 showed 38% VALU, 2.5 TB/s LLC, 7 TB/s L2 —
// nothing saturated, MLP=1 was the limiter).
#define ACC8(P, W)                                                             \
  {                                                                            \
    const u32 q0 = (u32)(P).x, q1 = (u32)(P).y, q2 = (u32)(P).z, q3 = (u32)(P).w; \
    acc[0] += (W)*bflo(q0);                                                    \
    acc[1] += (W)*bfhi(q0);                                                    \
    acc[2] += (W)*bflo(q1);                                                    \
    acc[3] += (W)*bfhi(q1);                                                    \
    acc[4] += (W)*bflo(q2);                                                    \
    acc[5] += (W)*bfhi(q2);                                                    \
    acc[6] += (W)*bflo(q3);                                                    \
    acc[7] += (W)*bfhi(q3);                                                    \
  }

template <bool RELU, bool FINAL>
__global__ __launch_bounds__(256) void agg_k(const u16* __restrict__ hb,
                                             const float* __restrict__ alsrc,
                                             const float* __restrict__ aldst,
                                             const int* __restrict__ rowptr,
                                             const int* __restrict__ esrc,
                                             const float* __restrict__ elw,
                                             const float* __restrict__ bias,
                                             u32* __restrict__ outB,
                                             float* __restrict__ outF,
                                             const int* __restrict__ flag) {
  const int n = blockIdx.x, t = threadIdx.x;
  const int lane = t & 63, wv = t >> 6;
  const int h = t & 7, eo = t >> 3;
  const int hh = lane >> 3;
  __shared__ float sw[8 * 260];
  __shared__ int ss[256];
  __shared__ float sred[32];
  __shared__ float smh[8], sd[8];
  __shared__ float red4[4][HC];
  const int beg = rowptr[n];
  const int deg = rowptr[n + 1] - beg;
  const float4 dd0 = *(const float4*)(aldst + (size_t)n * NHEAD);
  const float4 dd1 = *(const float4*)(aldst + (size_t)n * NHEAD + 4);
  const int chbase = lane * 8;
  float acc[8] = {};

  if (deg <= 256) {
    if (t < deg) {
      int e = beg + t;
      int s = esrc[e];
      float lw = elw[e];
      float4 q0 = *(const float4*)(alsrc + (size_t)s * NHEAD);
      float4 q1 = *(const float4*)(alsrc + (size_t)s * NHEAD + 4);
      float a;
      a = q0.x + dd0.x; a = (a > 0.f) ? a : NEG * a; sw[0 * 260 + t] = a + lw;
      a = q0.y + dd0.y; a = (a > 0.f) ? a : NEG * a; sw[1 * 260 + t] = a + lw;
      a = q0.z + dd0.z; a = (a > 0.f) ? a : NEG * a; sw[2 * 260 + t] = a + lw;
      a = q0.w + dd0.w; a = (a > 0.f) ? a : NEG * a; sw[3 * 260 + t] = a + lw;
      a = q1.x + dd1.x; a = (a > 0.f) ? a : NEG * a; sw[4 * 260 + t] = a + lw;
      a = q1.y + dd1.y; a = (a > 0.f) ? a : NEG * a; sw[5 * 260 + t] = a + lw;
      a = q1.z + dd1.z; a = (a > 0.f) ? a : NEG * a; sw[6 * 260 + t] = a + lw;
      a = q1.w + dd1.w; a = (a > 0.f) ? a : NEG * a; sw[7 * 260 + t] = a + lw;
      ss[t] = s;
    }
    __syncthreads();
    float m = -1e30f;
#pragma unroll
    for (int c = 0; c < 8; c++) {
      int j = c * 32 + eo;
      if (j < deg) m = fmaxf(m, sw[h * 260 + j]);
    }
    m = fmaxf(m, __shfl_xor(m, 8));
    m = fmaxf(m, __shfl_xor(m, 16));
    m = fmaxf(m, __shfl_xor(m, 32));
    if (lane < 8) sred[wv * 8 + lane] = m;
    __syncthreads();
    const float mh = fmaxf(fmaxf(sred[h], sred[8 + h]), fmaxf(sred[16 + h], sred[24 + h]));
    __syncthreads();
    float sum = 0.f;
#pragma unroll
    for (int c = 0; c < 8; c++) {
      int j = c * 32 + eo;
      if (j < deg) {
        float w = expf(sw[h * 260 + j] - mh);
        sw[h * 260 + j] = w;
        sum += w;
      }
    }
    sum += __shfl_xor(sum, 8);
    sum += __shfl_xor(sum, 16);
    sum += __shfl_xor(sum, 32);
    if (lane < 8) sred[wv * 8 + lane] = sum;
    __syncthreads();
    if (t < 8) sd[t] = sred[t] + sred[8 + t] + sred[16 + t] + sred[24 + t];
    // ---- pass B: one wave per edge, x4 unrolled for MLP ----
    int i = wv;
    for (; i + 12 < deg; i += 16) {
      const int s0 = ss[i], s1 = ss[i + 4], s2 = ss[i + 8], s3 = ss[i + 12];
      const float w0 = sw[hh * 260 + i], w1 = sw[hh * 260 + i + 4];
      const float w2 = sw[hh * 260 + i + 8], w3 = sw[hh * 260 + i + 12];
      const int4 p0 = *(const int4*)(hb + (size_t)s0 * HC + chbase);
      const int4 p1 = *(const int4*)(hb + (size_t)s1 * HC + chbase);
      const int4 p2 = *(const int4*)(hb + (size_t)s2 * HC + chbase);
      const int4 p3 = *(const int4*)(hb + (size_t)s3 * HC + chbase);
      ACC8(p0, w0)
      ACC8(p1, w1)
      ACC8(p2, w2)
      ACC8(p3, w3)
    }
    for (; i < deg; i += 4) {
      const int s = ss[i];
      const float w = sw[hh * 260 + i];
      const int4 p = *(const int4*)(hb + (size_t)s * HC + chbase);
      ACC8(p, w)
    }
  } else {
    const float aln = aldst[(size_t)n * NHEAD + h];
    float m = -1e30f;
    for (int j = eo; j < deg; j += 32) {
      int e = beg + j;
      float a = alsrc[(size_t)esrc[e] * NHEAD + h] + aln;
      a = (a > 0.f) ? a : NEG * a;
      m = fmaxf(m, a + elw[e]);
    }
    m = fmaxf(m, __shfl_xor(m, 8));
    m = fmaxf(m, __shfl_xor(m, 16));
    m = fmaxf(m, __shfl_xor(m, 32));
    if (lane < 8) sred[wv * 8 + lane] = m;
    __syncthreads();
    const float mh = fmaxf(fmaxf(sred[h], sred[8 + h]), fmaxf(sred[16 + h], sred[24 + h]));
    if (t < 8) smh[t] = mh;
    __syncthreads();
    float sum = 0.f;
    for (int j = eo; j < deg; j += 32) {
      int e = beg + j;
      float a = alsrc[(size_t)esrc[e] * NHEAD + h] + aln;
      a = (a > 0.f) ? a : NEG * a;
      sum += expf(a + elw[e] - mh);
    }
    sum += __shfl_xor(sum, 8);
    sum += __shfl_xor(sum, 16);
    sum += __shfl_xor(sum, 32);
    if (lane < 8) sred[wv * 8 + lane] = sum;
    __syncthreads();
    if (t < 8) sd[t] = sred[t] + sred[8 + t] + sred[16 + t] + sred[24 + t];
    for (int cb = 0; cb < deg; cb += 256) {
      int j = cb + t;
      if (j < deg) {
        int e = beg + j;
        int s = esrc[e];
        float lw = elw[e];
        float4 q0 = *(const float4*)(alsrc + (size_t)s * NHEAD);
        float4 q1 = *(const float4*)(alsrc + (size_t)s * NHEAD + 4);
        float a;
        a = q0.x + dd0.x; a = (a > 0.f) ? a : NEG * a; sw[0 * 260 + t] = expf(a + lw - smh[0]);
        a = q0.y + dd0.y; a = (a > 0.f) ? a : NEG * a; sw[1 * 260 + t] = expf(a + lw - smh[1]);
        a = q0.z + dd0.z; a = (a > 0.f) ? a : NEG * a; sw[2 * 260 + t] = expf(a + lw - smh[2]);
        a = q0.w + dd0.w; a = (a > 0.f) ? a : NEG * a; sw[3 * 260 + t] = expf(a + lw - smh[3]);
        a = q1.x + dd1.x; a = (a > 0.f) ? a : NEG * a; sw[4 * 260 + t] = expf(a + lw - smh[4]);
        a = q1.y + dd1.y; a = (a > 0.f) ? a : NEG * a; sw[5 * 260 + t] = expf(a + lw - smh[5]);
        a = q1.z + dd1.z; a = (a > 0.f) ? a : NEG * a; sw[6 * 260 + t] = expf(a + lw - smh[6]);
        a = q1.w + dd1.w; a = (a > 0.f) ? a : NEG * a; sw[7 * 260 + t] = expf(a + lw - smh[7]);
        ss[t] = s;
      }
      __syncthreads();
      int cnt = min(256, deg - cb);
      for (int i = wv; i < cnt; i += 4) {
        const int s = ss[i];
        const float w = sw[hh * 260 + i];
        const int4 p = *(const int4*)(hb + (size_t)s * HC + chbase);
        ACC8(p, w)
      }
      __syncthreads();
    }
  }
  // ---- cross-wave channel reduction + epilogue ----
#pragma unroll
  for (int j = 0; j < 8; j++) red4[wv][chbase + j] = acc[j];
  __syncthreads();
  const int c0 = 2 * t;
  float v0 = red4[0][c0] + red4[1][c0] + red4[2][c0] + red4[3][c0];
  float v1 = red4[0][c0 + 1] + red4[1][c0 + 1] + red4[2][c0 + 1] + red4[3][c0 + 1];
  const float inv = 1.f / sd[t >> 5];
  v0 = v0 * inv + bias[c0];
  v1 = v1 * inv + bias[c0 + 1];
  if (RELU) {
    v0 = fmaxf(v0, 0.f);
    v1 = fmaxf(v1, 0.f);
  }
  if (FINAL && !(*flag)) {
    outF[(size_t)n * HC + c0] = v0;
    outF[(size_t)n * HC + c0 + 1] = v1;
  } else {
    outB[(size_t)n * (HC / 2) + t] = (u32)f2bf(v0) | ((u32)f2bf(v1) << 16);
  }
}

// ---------------- workspace layout -----------------------------------------
static constexpr size_t algn(size_t x) { return (x + 255) & ~(size_t)255; }
static constexpr size_t oFlag = 0;
static constexpr size_t oXB = algn(oFlag + 256);
static constexpr size_t oW1T = algn(oXB + (size_t)SX * 2);
static constexpr size_t oW2T = algn(oW1T + (size_t)CIN * HC * 2);
static constexpr size_t oAtt = algn(oW2T + (size_t)HC * HC * 2);
static constexpr size_t oHB = algn(oAtt + (size_t)SATT * 4);
static constexpr size_t oO1B = algn(oHB + (size_t)NN * HC * 2);
static constexpr size_t oAS = algn(oO1B + (size_t)NN * HC * 2);
static constexpr size_t oAD = algn(oAS + (size_t)NN * NHEAD * 4);
static constexpr size_t oRP = algn(oAD + (size_t)NN * NHEAD * 4);
static constexpr size_t oCnt = algn(oRP + (size_t)(NN + 1) * 4);
static constexpr size_t oWcur = algn(oCnt + (size_t)NN * 4);
static constexpr size_t oESrc = algn(oWcur + (size_t)NN * 4);
static constexpr size_t oELW = algn(oESrc + (size_t)ETOT * 4);

extern "C" void kernel_launch(void* const* d_in, const int* in_sizes, int n_in,
                              void* d_out, int out_size, void* d_ws, size_t ws_size,
                              hipStream_t stream) {
  (void)in_sizes; (void)n_in; (void)out_size; (void)ws_size;
  const int* ei = (const int*)d_in[1];

  char* ws = (char*)d_ws;
  int* flag = (int*)(ws + oFlag);
  u16* xb = (u16*)(ws + oXB);
  u16* w1t = (u16*)(ws + oW1T);
  u16* w2t = (u16*)(ws + oW2T);
  float* attf = (float*)(ws + oAtt);
  float* as1f = attf, *ad1f = attf + 512, *b1f = attf + 1024;
  float* as2f = attf + 1536, *ad2f = attf + 2048, *b2f = attf + 2560;
  u16* hb = (u16*)(ws + oHB);
  u16* o1b = (u16*)(ws + oO1B);
  float* alsrc = (float*)(ws + oAS);
  float* aldst = (float*)(ws + oAD);
  int* rowptr = (int*)(ws + oRP);
  int* counts = (int*)(ws + oCnt);
  int* wcur = (int*)(ws + oWcur);
  int* esrc = (int*)(ws + oESrc);
  float* elw = (float*)(ws + oELW);

  hipMemsetAsync(counts, 0, (size_t)NN * 4, stream);
  prep_k<<<PB_TOT, 256, 0, stream>>>(d_in[0], d_in[3], d_in[7],
                                     d_in[4], d_in[5], d_in[6],
                                     d_in[8], d_in[9], d_in[10], ei,
                                     xb, w1t, w2t, attf, counts, flag);
  scan_k<<<1, 1024, 0, stream>>>(counts, rowptr, wcur);
  fill_k<<<(ETOT + 255) / 256, 256, 0, stream>>>(ei, d_in[2], flag, wcur, esrc, elw);

  // ---- layer 1 ----
  gemm_mfma<<<dim3(HC / BN, (NN + BM - 1) / BM), 256, 0, stream>>>(
      xb, d_in[0], flag, w1t, as1f, ad1f, hb, alsrc, aldst, NN, CIN);
  agg_k<true, false><<<NN, 256, 0, stream>>>(hb, alsrc, aldst, rowptr, esrc, elw,
                                             b1f, (u32*)o1b, nullptr, flag);

  // ---- layer 2 ----
  gemm_mfma<<<dim3(HC / BN, (NN + BM - 1) / BM), 256, 0, stream>>>(
      o1b, nullptr, nullptr, w2t, as2f, ad2f, hb, alsrc, aldst, NN, HC);
  agg_k<false, true><<<NN, 256, 0, stream>>>(hb, alsrc, aldst, rowptr, esrc, elw,
                                             b2f, (u32*)d_out, (float*)d_out, flag);
}

// Round 10
// 259.362 us; speedup vs baseline: 4.5176x; 1.0174x over previous
//
#include <hip/hip_runtime.h>
#include <hip/hip_bf16.h>

#define NN 10000
#define EE 320000
#define ETOT (EE + NN)
#define CIN 256
#define HC 512
#define NHEAD 8
#define NEG 0.2f

#define SX (NN * CIN)
#define SATT (6 * 512)

using bf16x8 = __attribute__((ext_vector_type(8))) short;
using f32x4 = __attribute__((ext_vector_type(4))) float;
typedef unsigned short u16;
typedef unsigned int u32;

__device__ __forceinline__ u16 f2bf(float f) {
  __hip_bfloat16 b = __float2bfloat16(f);
  return *(u16*)&b;
}
__device__ __forceinline__ float bflo(u32 p) { return __uint_as_float(p << 16); }
__device__ __forceinline__ float bfhi(u32 p) { return __uint_as_float(p & 0xFFFF0000u); }

// ============ prep: detect + convert + degree-count + W transpose ==========
#define PB_X ((SX + 255) / 256)
#define PB_ATT ((SATT + 255) / 256)
#define PB_CNT ((ETOT + 255) / 256)
#define PB_WT 96
#define PB_TOT (PB_X + PB_ATT + PB_CNT + PB_WT)

__global__ __launch_bounds__(256) void prep_k(
    const void* __restrict__ x, const void* __restrict__ w1,
    const void* __restrict__ w2,
    const void* a0, const void* a1, const void* a2,
    const void* a3, const void* a4, const void* a5,
    const int* __restrict__ ei,
    u16* __restrict__ xb, u16* __restrict__ w1t, u16* __restrict__ w2t,
    float* __restrict__ attf, int* __restrict__ counts, int* __restrict__ flag) {
  const int b = blockIdx.x, t = threadIdx.x;
  __shared__ int sbad;
  if (t == 0) sbad = 0;
  __syncthreads();
  {
    const u16* xu = (const u16*)x;
    unsigned e0 = (xu[2 * t] >> 7) & 0xFFu;
    unsigned e1 = (xu[2 * t + 1] >> 7) & 0xFFu;
    if (e0 >= 0xC8u || e1 >= 0xC8u) sbad = 1;
  }
  __syncthreads();
  const bool bf = (sbad == 0);
  if (b == 0 && t == 0) *flag = bf ? 1 : 0;

  if (b < PB_X) {
    if (!bf) {
      int i = b * 256 + t;
      if (i < SX) xb[i] = f2bf(((const float*)x)[i]);
    }
  } else if (b < PB_X + PB_ATT) {
    int j = (b - PB_X) * 256 + t;
    if (j < SATT) {
      const void* ps[6] = {a0, a1, a2, a3, a4, a5};
      const void* p = ps[j >> 9];
      int k = j & 511;
      attf[j] = bf ? __bfloat162float(((const __hip_bfloat16*)p)[k])
                   : ((const float*)p)[k];
    }
  } else if (b < PB_X + PB_ATT + PB_CNT) {
    int e = (b - PB_X - PB_ATT) * 256 + t;
    if (e < ETOT) {
      int d = (e < EE) ? ei[EE + e] : (e - EE);
      atomicAdd(&counts[d], 1);
    }
  } else {
    __shared__ u16 tile[64][72];
    int wb = b - (PB_X + PB_ATT + PB_CNT);
    const void* src;
    u16* dst;
    int K, tk, tn;
    if (wb < 32) { src = w1; dst = w1t; K = CIN; tk = (wb >> 3) * 64; tn = (wb & 7) * 64; }
    else { wb -= 32; src = w2; dst = w2t; K = HC; tk = (wb >> 3) * 64; tn = (wb & 7) * 64; }
    const int r = t >> 2, cb = (t & 3) * 16;
    if (bf) {
      const u16* s = (const u16*)src + (size_t)(tk + r) * HC + tn + cb;
      *(int4*)&tile[r][cb] = ((const int4*)s)[0];
      *(int4*)&tile[r][cb + 8] = ((const int4*)s)[1];
    } else {
      const float* s = (const float*)src + (size_t)(tk + r) * HC + tn + cb;
#pragma unroll
      for (int j = 0; j < 16; j++) tile[r][cb + j] = f2bf(s[j]);
    }
    __syncthreads();
    union { u16 o[16]; int4 v[2]; } u;
#pragma unroll
    for (int j = 0; j < 16; j++) u.o[j] = tile[cb + j][r];
    int4* dp = (int4*)(dst + (size_t)(tn + r) * K + tk + cb);
    dp[0] = u.v[0];
    dp[1] = u.v[1];
  }
}

// ============ exclusive scan: rowptr + working cursors ======================
__global__ __launch_bounds__(1024) void scan_k(const int* __restrict__ counts,
                                               int* __restrict__ rowptr,
                                               int* __restrict__ wcur) {
  __shared__ int buf[1024];
  const int t = threadIdx.x;
  int loc[10];
  int s = 0;
#pragma unroll
  for (int j = 0; j < 10; j++) {
    int i = t * 10 + j;
    s += (i < NN) ? counts[i] : 0;
    loc[j] = s;
  }
  buf[t] = s;
  __syncthreads();
  for (int off = 1; off < 1024; off <<= 1) {
    int v = (t >= off) ? buf[t - off] : 0;
    __syncthreads();
    buf[t] += v;
    __syncthreads();
  }
  int base = (t > 0) ? buf[t - 1] : 0;
  int prev = 0;
#pragma unroll
  for (int j = 0; j < 10; j++) {
    int i = t * 10 + j;
    if (i < NN) {
      rowptr[i + 1] = base + loc[j];
      wcur[i] = base + prev;
    }
    prev = loc[j];
  }
  if (t == 0) rowptr[0] = 0;
}

// ============ CSR fill ======================================================
__global__ void fill_k(const int* __restrict__ ei, const void* __restrict__ ew,
                       const int* __restrict__ flag, int* __restrict__ wcur,
                       int* __restrict__ esrc, float* __restrict__ elw) {
  int e = blockIdx.x * blockDim.x + threadIdx.x;
  if (e >= ETOT) return;
  int s, d;
  float lw;
  if (e < EE) {
    s = ei[e];
    d = ei[EE + e];
    float w = (*flag) ? __bfloat162float(((const __hip_bfloat16*)ew)[e])
                      : ((const float*)ew)[e];
    lw = log2f(w);
  } else {
    s = d = e - EE;
    lw = 0.f;
  }
  int pos = atomicAdd(&wcur[d], 1);
  esrc[pos] = s;
  elw[pos] = lw;
}

// ============ MFMA GEMM + fused logits ======================================
#define BM 64
#define BN 128
#define BK 64
#define LSTR 72

__global__ __launch_bounds__(256) void gemm_mfma(const u16* __restrict__ A,
                                                 const void* __restrict__ Axalt,
                                                 const int* __restrict__ flagp,
                                                 const u16* __restrict__ Wt,
                                                 const float* __restrict__ as_w,
                                                 const float* __restrict__ ad_w,
                                                 u16* __restrict__ hb,
                                                 float* __restrict__ alsrc,
                                                 float* __restrict__ aldst,
                                                 int M, int K) {
  __shared__ u16 As[BM * LSTR];
  __shared__ u16 Bs[BN * LSTR];
  __shared__ float sps[2][2][BM], spd[2][2][BM];
  const u16* Asel = (flagp && *flagp) ? (const u16*)Axalt : A;
  const int bx = blockIdx.x;
  const int bm = blockIdx.y * BM, bn = bx * BN;
  const int t = threadIdx.x, wv = t >> 6, lane = t & 63;
  const int l15 = lane & 15, quad = lane >> 4;
  f32x4 acc[4][2] = {};
  for (int k0 = 0; k0 < K; k0 += BK) {
    {
      int row = t >> 2, kq = (t & 3) * 16;
      int gr = bm + row;
      int4 v0 = make_int4(0, 0, 0, 0), v1 = v0;
      if (gr < M) {
        const int4* gp = (const int4*)(Asel + (size_t)gr * K + k0 + kq);
        v0 = gp[0];
        v1 = gp[1];
      }
      int4* lp = (int4*)(As + row * LSTR + kq);
      lp[0] = v0;
      lp[1] = v1;
    }
    {
      int row = t >> 1, kq = (t & 1) * 32;
      const int4* gp = (const int4*)(Wt + (size_t)(bn + row) * K + k0 + kq);
      int4* lp = (int4*)(Bs + row * LSTR + kq);
      lp[0] = gp[0];
      lp[1] = gp[1];
      lp[2] = gp[2];
      lp[3] = gp[3];
    }
    __syncthreads();
#pragma unroll
    for (int kk = 0; kk < 2; kk++) {
      bf16x8 bfr[2];
#pragma unroll
      for (int ct = 0; ct < 2; ct++)
        bfr[ct] = *(const bf16x8*)(Bs + (wv * 32 + ct * 16 + l15) * LSTR + kk * 32 + quad * 8);
#pragma unroll
      for (int rt = 0; rt < 4; rt++) {
        bf16x8 af = *(const bf16x8*)(As + (rt * 16 + l15) * LSTR + kk * 32 + quad * 8);
#pragma unroll
        for (int ct = 0; ct < 2; ct++)
          acc[rt][ct] = __builtin_amdgcn_mfma_f32_16x16x32_bf16(af, bfr[ct],
                                                                acc[rt][ct], 0, 0, 0);
      }
    }
    __syncthreads();
  }
  const int head = bx * 2 + (wv >> 1);
  float asw[2], adw[2];
#pragma unroll
  for (int ct = 0; ct < 2; ct++) {
    int c = head * 64 + (wv & 1) * 32 + ct * 16 + l15;
    asw[ct] = as_w[c];
    adw[ct] = ad_w[c];
  }
#pragma unroll
  for (int rt = 0; rt < 4; rt++) {
#pragma unroll
    for (int r = 0; r < 4; r++) {
      int rib = rt * 16 + quad * 4 + r;
      int row = bm + rib;
      float ps = 0.f, pd = 0.f;
#pragma unroll
      for (int ct = 0; ct < 2; ct++) {
        float v = acc[rt][ct][r];
        ps += v * asw[ct];
        pd += v * adw[ct];
        if (row < M)
          hb[(size_t)row * HC + bn + wv * 32 + ct * 16 + l15] = f2bf(v);
      }
#pragma unroll
      for (int d = 1; d < 16; d <<= 1) {
        ps += __shfl_xor(ps, d);
        pd += __shfl_xor(pd, d);
      }
      if (l15 == 0) {
        sps[wv >> 1][wv & 1][rib] = ps;
        spd[wv >> 1][wv & 1][rib] = pd;
      }
    }
  }
  __syncthreads();
  if (t < 2 * BM) {
    int rib = t & 63, hs = t >> 6;
    int row = bm + rib;
    if (row < M) {
      alsrc[row * NHEAD + bx * 2 + hs] = sps[hs][0][rib] + sps[hs][1][rib];
      aldst[row * NHEAD + bx * 2 + hs] = spd[hs][0][rib] + spd[hs][1][rib];
    }
  }
}

// ============ barrier-free per-wave segment softmax + aggregation ===========
// One WAVE per dst node (node = 4*blockIdx + wv). Per-wave-private LDS slice
// holds alpha[8 head][132] + src[128]; all reductions are shfl_xor (wave-
// local) -> ZERO __syncthreads in the kernel. Pass B: x4-unrolled int4 row
// gathers, weight from own LDS, per-head denom via __shfl broadcast.
#define ACC8(P, W)                                                             \
  {                                                                            \
    const u32 q0 = (u32)(P).x, q1 = (u32)(P).y, q2 = (u32)(P).z, q3 = (u32)(P).w; \
    acc[0] += (W)*bflo(q0);                                                    \
    acc[1] += (W)*bfhi(q0);                                                    \
    acc[2] += (W)*bflo(q1);                                                    \
    acc[3] += (W)*bfhi(q1);                                                    \
    acc[4] += (W)*bflo(q2);                                                    \
    acc[5] += (W)*bfhi(q2);                                                    \
    acc[6] += (W)*bflo(q3);                                                    \
    acc[7] += (W)*bfhi(q3);                                                    \
  }

template <bool RELU, bool FINAL>
__global__ __launch_bounds__(256) void agg_k(const u16* __restrict__ hb,
                                             const float* __restrict__ alsrc,
                                             const float* __restrict__ aldst,
                                             const int* __restrict__ rowptr,
                                             const int* __restrict__ esrc,
                                             const float* __restrict__ elw,
                                             const float* __restrict__ bias,
                                             u32* __restrict__ outB,
                                             float* __restrict__ outF,
                                             const int* __restrict__ flag) {
  const int t = threadIdx.x;
  const int wv = t >> 6, lane = t & 63;
  const int n = blockIdx.x * 4 + wv;
  const int h = lane & 7, eo = lane >> 3;   // pass-A mapping
  const int hh = lane >> 3;                 // pass-B head (channels lane*8..+7)
  const int chbase = lane * 8;
  __shared__ float swA[4][NHEAD][132];
  __shared__ int ssA[4][128];
  float (*const swv)[132] = swA[wv];
  int* const ssv = ssA[wv];
  const int beg = rowptr[n];
  const int deg = rowptr[n + 1] - beg;
  const float aln = aldst[(size_t)n * NHEAD + h];
  float acc[8] = {};
  float inv;

  if (deg <= 128) {
    // ---- A1: alpha -> LDS, track max ----
    float m = -1e30f;
    for (int j = eo; j < deg; j += 8) {
      int e = beg + j;
      int s = esrc[e];
      float a = alsrc[(size_t)s * NHEAD + h] + aln;
      a = (a > 0.f) ? a : NEG * a;
      a += elw[e];
      swv[h][j] = a;
      m = fmaxf(m, a);
      if (h == 0) ssv[j] = s;
    }
    m = fmaxf(m, __shfl_xor(m, 8));
    m = fmaxf(m, __shfl_xor(m, 16));
    m = fmaxf(m, __shfl_xor(m, 32));
    // ---- A2: exp in place + denom ----
    float sum = 0.f;
    for (int j = eo; j < deg; j += 8) {
      float w = expf(swv[h][j] - m);
      swv[h][j] = w;
      sum += w;
    }
    sum += __shfl_xor(sum, 8);
    sum += __shfl_xor(sum, 16);
    sum += __shfl_xor(sum, 32);
    inv = 1.f / __shfl(sum, hh);  // denom of head hh lives in lane hh
    // ---- B: sequential edges, x4 unrolled ----
    int i = 0;
    for (; i + 3 < deg; i += 4) {
      const int s0 = ssv[i], s1 = ssv[i + 1], s2 = ssv[i + 2], s3 = ssv[i + 3];
      const float w0 = swv[hh][i], w1 = swv[hh][i + 1];
      const float w2 = swv[hh][i + 2], w3 = swv[hh][i + 3];
      const int4 p0 = *(const int4*)(hb + (size_t)s0 * HC + chbase);
      const int4 p1 = *(const int4*)(hb + (size_t)s1 * HC + chbase);
      const int4 p2 = *(const int4*)(hb + (size_t)s2 * HC + chbase);
      const int4 p3 = *(const int4*)(hb + (size_t)s3 * HC + chbase);
      ACC8(p0, w0)
      ACC8(p1, w1)
      ACC8(p2, w2)
      ACC8(p3, w3)
    }
    for (; i < deg; i++) {
      const int s = ssv[i];
      const float w = swv[hh][i];
      const int4 p = *(const int4*)(hb + (size_t)s * HC + chbase);
      ACC8(p, w)
    }
  } else {
    // ---- slow path (deg > 128): streaming recompute, still barrier-free ----
    float m = -1e30f;
    for (int j = eo; j < deg; j += 8) {
      int e = beg + j;
      float a = alsrc[(size_t)esrc[e] * NHEAD + h] + aln;
      a = (a > 0.f) ? a : NEG * a;
      m = fmaxf(m, a + elw[e]);
    }
    m = fmaxf(m, __shfl_xor(m, 8));
    m = fmaxf(m, __shfl_xor(m, 16));
    m = fmaxf(m, __shfl_xor(m, 32));
    float sum = 0.f;
    for (int j = eo; j < deg; j += 8) {
      int e = beg + j;
      float a = alsrc[(size_t)esrc[e] * NHEAD + h] + aln;
      a = (a > 0.f) ? a : NEG * a;
      sum += expf(a + elw[e] - m);
    }
    sum += __shfl_xor(sum, 8);
    sum += __shfl_xor(sum, 16);
    sum += __shfl_xor(sum, 32);
    inv = 1.f / __shfl(sum, hh);
    const float mh = __shfl(m, hh);
    const float alnh = __shfl(aln, hh);
    for (int i = 0; i < deg; i++) {
      int e = beg + i;
      int s = esrc[e];  // uniform address -> broadcast
      float a = alsrc[(size_t)s * NHEAD + hh] + alnh;
      a = (a > 0.f) ? a : NEG * a;
      float w = expf(a + elw[e] - mh);
      const int4 p = *(const int4*)(hb + (size_t)s * HC + chbase);
      ACC8(p, w)
    }
  }
  // ---- epilogue: normalize + bias (+relu) + store (wave-local) ----
  const float4 b0 = *(const float4*)(bias + chbase);
  const float4 b1 = *(const float4*)(bias + chbase + 4);
  float v[8];
  v[0] = acc[0] * inv + b0.x; v[1] = acc[1] * inv + b0.y;
  v[2] = acc[2] * inv + b0.z; v[3] = acc[3] * inv + b0.w;
  v[4] = acc[4] * inv + b1.x; v[5] = acc[5] * inv + b1.y;
  v[6] = acc[6] * inv + b1.z; v[7] = acc[7] * inv + b1.w;
  if (RELU) {
#pragma unroll
    for (int k = 0; k < 8; k++) v[k] = fmaxf(v[k], 0.f);
  }
  if (FINAL && !(*flag)) {
    float4* op = (float4*)(outF + (size_t)n * HC + chbase);
    op[0] = make_float4(v[0], v[1], v[2], v[3]);
    op[1] = make_float4(v[4], v[5], v[6], v[7]);
  } else {
    int4 pk;
    pk.x = (int)((u32)f2bf(v[0]) | ((u32)f2bf(v[1]) << 16));
    pk.y = (int)((u32)f2bf(v[2]) | ((u32)f2bf(v[3]) << 16));
    pk.z = (int)((u32)f2bf(v[4]) | ((u32)f2bf(v[5]) << 16));
    pk.w = (int)((u32)f2bf(v[6]) | ((u32)f2bf(v[7]) << 16));
    *(int4*)(outB + (size_t)n * (HC / 2) + lane * 4) = pk;
  }
}

// ---------------- workspace layout -----------------------------------------
static constexpr size_t algn(size_t x) { return (x + 255) & ~(size_t)255; }
static constexpr size_t oFlag = 0;
static constexpr size_t oXB = algn(oFlag + 256);
static constexpr size_t oW1T = algn(oXB + (size_t)SX * 2);
static constexpr size_t oW2T = algn(oW1T + (size_t)CIN * HC * 2);
static constexpr size_t oAtt = algn(oW2T + (size_t)HC * HC * 2);
static constexpr size_t oHB = algn(oAtt + (size_t)SATT * 4);
static constexpr size_t oO1B = algn(oHB + (size_t)NN * HC * 2);
static constexpr size_t oAS = algn(oO1B + (size_t)NN * HC * 2);
static constexpr size_t oAD = algn(oAS + (size_t)NN * NHEAD * 4);
static constexpr size_t oRP = algn(oAD + (size_t)NN * NHEAD * 4);
static constexpr size_t oCnt = algn(oRP + (size_t)(NN + 1) * 4);
static constexpr size_t oWcur = algn(oCnt + (size_t)NN * 4);
static constexpr size_t oESrc = algn(oWcur + (size_t)NN * 4);
static constexpr size_t oELW = algn(oESrc + (size_t)ETOT * 4);

extern "C" void kernel_launch(void* const* d_in, const int* in_sizes, int n_in,
                              void* d_out, int out_size, void* d_ws, size_t ws_size,
                              hipStream_t stream) {
  (void)in_sizes; (void)n_in; (void)out_size; (void)ws_size;
  const int* ei = (const int*)d_in[1];

  char* ws = (char*)d_ws;
  int* flag = (int*)(ws + oFlag);
  u16* xb = (u16*)(ws + oXB);
  u16* w1t = (u16*)(ws + oW1T);
  u16* w2t = (u16*)(ws + oW2T);
  float* attf = (float*)(ws + oAtt);
  float* as1f = attf, *ad1f = attf + 512, *b1f = attf + 1024;
  float* as2f = attf + 1536, *ad2f = attf + 2048, *b2f = attf + 2560;
  u16* hb = (u16*)(ws + oHB);
  u16* o1b = (u16*)(ws + oO1B);
  float* alsrc = (float*)(ws + oAS);
  float* aldst = (float*)(ws + oAD);
  int* rowptr = (int*)(ws + oRP);
  int* counts = (int*)(ws + oCnt);
  int* wcur = (int*)(ws + oWcur);
  int* esrc = (int*)(ws + oESrc);
  float* elw = (float*)(ws + oELW);

  hipMemsetAsync(counts, 0, (size_t)NN * 4, stream);
  prep_k<<<PB_TOT, 256, 0, stream>>>(d_in[0], d_in[3], d_in[7],
                                     d_in[4], d_in[5], d_in[6],
                                     d_in[8], d_in[9], d_in[10], ei,
                                     xb, w1t, w2t, attf, counts, flag);
  scan_k<<<1, 1024, 0, stream>>>(counts, rowptr, wcur);
  fill_k<<<(ETOT + 255) / 256, 256, 0, stream>>>(ei, d_in[2], flag, wcur, esrc, elw);

  // ---- layer 1 ----
  gemm_mfma<<<dim3(HC / BN, (NN + BM - 1) / BM), 256, 0, stream>>>(
      xb, d_in[0], flag, w1t, as1f, ad1f, hb, alsrc, aldst, NN, CIN);
  agg_k<true, false><<<NN / 4, 256, 0, stream>>>(hb, alsrc, aldst, rowptr, esrc, elw,
                                                 b1f, (u32*)o1b, nullptr, flag);

  // ---- layer 2 ----
  gemm_mfma<<<dim3(HC / BN, (NN + BM - 1) / BM), 256, 0, stream>>>(
      o1b, nullptr, nullptr, w2t, as2f, ad2f, hb, alsrc, aldst, NN, HC);
  agg_k<false, true><<<NN / 4, 256, 0, stream>>>(hb, alsrc, aldst, rowptr, esrc, elw,
                                                 b2f, (u32*)d_out, (float*)d_out, flag);
}